// Round 11
// baseline (610.522 us; speedup 1.0000x reference)
//
#include <hip/hip_runtime.h>
#include <hip/hip_bf16.h>

#define EPSBN 2e-5f

typedef __attribute__((ext_vector_type(8))) short short8v;
typedef __attribute__((ext_vector_type(4))) float f32x4;

__device__ inline unsigned short f2bf(float f) {
  unsigned u = __float_as_uint(f);
  unsigned r = (u + 0x7FFFu + ((u >> 16) & 1u)) >> 16;
  return (unsigned short)r;
}
__device__ inline float bf2f(unsigned short h) {
  return __uint_as_float(((unsigned)h) << 16);
}

// DPP row-rotate float add: v += rotate_within_16(v, N). VALU pipe, not LDS.
template <int CTRL>
__device__ inline float dpp_radd(float v) {
  int r = __builtin_amdgcn_update_dpp(0, __float_as_int(v), CTRL, 0xf, 0xf,
                                      true);
  return v + __int_as_float(r);
}

// ---------------------------------------------------------------------------
// Per-scale pair-packed B source, INTERLEAVED: for scale s (dilation d=2^s),
//   xpair[(s*8+b)*PROW + i] = ( hi(x[i])|hi(x[i+d])<<16 ,
//                               lo(x[i])|lo(x[i+d])<<16 )
// One uint2 element carries both MFMA operand words -> lift stages with 12
// dwordx2 loads instead of 24 dword loads (halves VMEM insts + addr VALU).
// pad_x folded in (split recomputed per-s from x; write-bound kernel).
// ---------------------------------------------------------------------------
constexpr int XPADL = 9984;
constexpr int XPADR = 14336;
constexpr int PROW = XPADL + 32768 + XPADR;  // 57088

__global__ __launch_bounds__(256) void pad_pair_kernel(
    const float* __restrict__ x, uint2* __restrict__ xpair) {
  const int i = blockIdx.x * 256 + threadIdx.x;
  if (i >= PROW) return;
  const int sb = blockIdx.y;  // s*8 + b
  const int s = sb >> 3;
  const int b = sb & 7;
  const int d = 1 << s;
  const int pos0 = i - XPADL;
  const int pos1 = pos0 + d;
  float v0 = (pos0 >= 0 && pos0 < 32768) ? x[b * 32768 + pos0] : 0.f;
  float v1 = (pos1 >= 0 && pos1 < 32768) ? x[b * 32768 + pos1] : 0.f;
  unsigned u0 = __float_as_uint(v0);
  unsigned h0 = u0 >> 16;
  unsigned lo0 =
      __float_as_uint(v0 - __uint_as_float(u0 & 0xffff0000u)) >> 16;
  unsigned u1 = __float_as_uint(v1);
  unsigned h1 = u1 >> 16;
  unsigned lo1 =
      __float_as_uint(v1 - __uint_as_float(u1 & 0xffff0000u)) >> 16;
  uint2 o;
  o.x = h0 | (h1 << 16);
  o.y = lo0 | (lo1 << 16);
  xpair[(size_t)sb * PROW + i] = o;
}

// ---------------------------------------------------------------------------
// Pack w1 [51][79] -> per-s split bf16 (1/2^s folded), [s][hi/lo][64][96]
// ---------------------------------------------------------------------------
__global__ __launch_bounds__(256) void pack_w1_kernel(
    const float* __restrict__ W, short* __restrict__ A) {
  int idx = blockIdx.x * 256 + threadIdx.x;
  if (idx >= 9 * 64 * 96) return;
  int s = idx / (64 * 96);
  int rem = idx - s * 64 * 96;
  int co = rem / 96;
  int k = rem - co * 96;
  float v = 0.f;
  if (co < 51 && k < 79)
    v = W[co * 79 + k] * __uint_as_float((unsigned)(127 - s) << 23);
  unsigned short hi = f2bf(v);
  unsigned short lo = f2bf(v - bf2f(hi));
  A[(size_t)s * 2 * 64 * 96 + co * 96 + k] = (short)hi;
  A[(size_t)s * 2 * 64 * 96 + 64 * 96 + co * 96 + k] = (short)lo;
}

// ---------------------------------------------------------------------------
// lift_mfma: MFMA GEMM + fused pool4 + DPP stats reduce. y1 fp32 (bf16 y1
// broke absmax in R9). Staging via interleaved uint2 dwordx2 loads.
// ---------------------------------------------------------------------------
__global__ __launch_bounds__(256) void lift_mfma_kernel(
    const uint2* __restrict__ xpair, const short* __restrict__ Apk1,
    float* __restrict__ y1, float* __restrict__ part1) {
  constexpr int P = 104;
  const int bid = blockIdx.x;
  const int lc = (bid & 7) * 64 + (bid >> 3);  // 512 = 8*64, bijective
  const int s = blockIdx.y;
  const int b = blockIdx.z;
  const int d = 1 << s;
  const int l0 = lc * 64;
  const int tid = threadIdx.x;
  const int lane = tid & 63;
  const int quad = lane >> 4;
  const int n0 = lane & 15;
  const int wv = tid >> 6;
  const int coBase = wv * 16;

  __shared__ __align__(16) short Bh[64 * P];
  __shared__ __align__(16) short Bl[64 * P];
  __shared__ float sCh[2][64];

  const int nB = tid & 63;
  const int rowW = ((nB & 3) << 4) | (nB >> 2);  // LDS row permutation
  const int swzW = (nB & 3) << 3;                // write slot XOR (shorts)
  const int ogu = __builtin_amdgcn_readfirstlane(tid >> 6);
  const uint2* xq = xpair + (size_t)(s * 8 + b) * PROW + XPADL + l0;

#pragma unroll
  for (int r = 0; r < 3; ++r) {
    const int kb = (ogu + 4 * r) * 8;
    const int base = (kb - 39) * d;
    uint2 q0 = xq[base + nB];
    uint2 q1 = xq[base + 2 * d + nB];
    uint2 q2 = xq[base + 4 * d + nB];
    uint2 q3 = xq[base + 6 * d + nB];
    uint4 ph, pl;
    ph.x = q0.x;
    ph.y = q1.x;
    ph.z = q2.x;
    ph.w = q3.x;
    pl.x = q0.y;
    pl.y = q1.y;
    pl.z = q2.y;
    pl.w = q3.y;
    *(uint4*)(Bh + rowW * P + (kb ^ swzW)) = ph;
    *(uint4*)(Bl + rowW * P + (kb ^ swzW)) = pl;
  }

  const short* ApkS = Apk1 + (size_t)s * 2 * 64 * 96;
  const short* arowH = ApkS + (coBase + n0) * 96;
  const short* arowL = arowH + 64 * 96;

  __syncthreads();

  f32x4 acc[4];
#pragma unroll
  for (int t = 0; t < 4; ++t) acc[t] = (f32x4){0.f, 0.f, 0.f, 0.f};

#pragma unroll
  for (int ks = 0; ks < 3; ++ks) {
    short8v ah = *(const short8v*)(arowH + ks * 32 + quad * 8);
    short8v al = *(const short8v*)(arowL + ks * 32 + quad * 8);
#pragma unroll
    for (int t = 0; t < 4; ++t) {
      const int n = n0 + 16 * t;
      const int off = (ks * 32 + quad * 8) ^ (t << 3);
      short8v bh = *(const short8v*)(Bh + n * P + off);
      short8v bl = *(const short8v*)(Bl + n * P + off);
      acc[t] = __builtin_amdgcn_mfma_f32_16x16x32_bf16(ah, bh, acc[t], 0, 0, 0);
      acc[t] = __builtin_amdgcn_mfma_f32_16x16x32_bf16(ah, bl, acc[t], 0, 0, 0);
      acc[t] = __builtin_amdgcn_mfma_f32_16x16x32_bf16(al, bh, acc[t], 0, 0, 0);
    }
  }

#pragma unroll
  for (int reg = 0; reg < 4; ++reg) {
    const int co = coBase + quad * 4 + reg;
    float po = fmaxf(fmaxf(acc[0][reg], acc[1][reg]),
                     fmaxf(acc[2][reg], acc[3][reg]));
    const bool valid = (co < 51);
    if (valid) {
      y1[(((size_t)b * 51 + co) * 9 + s) * 8192 + (l0 >> 2) + n0] = po;
    }
    float us = valid ? po : 0.f;
    float sq = us * us;
    us = dpp_radd<0x128>(us);
    sq = dpp_radd<0x128>(sq);
    us = dpp_radd<0x124>(us);
    sq = dpp_radd<0x124>(sq);
    us = dpp_radd<0x122>(us);
    sq = dpp_radd<0x122>(sq);
    us = dpp_radd<0x121>(us);
    sq = dpp_radd<0x121>(sq);
    if (n0 == 0) {
      sCh[0][co] = us;
      sCh[1][co] = sq;
    }
  }
  __syncthreads();
  if (tid < 51) {
    float* pp = part1 + (size_t)lc * 128;
    atomicAdd(&pp[tid], sCh[0][tid]);
    atomicAdd(&pp[64 + tid], sCh[1][tid]);
  }
}

// ---------------------------------------------------------------------------
// Reduce the 512 lc-sliced stats partials into st.
// ---------------------------------------------------------------------------
__global__ __launch_bounds__(128) void reduce_stats1_kernel(
    const float* __restrict__ p, float* __restrict__ st) {
  const int t = threadIdx.x;
  if (t >= 102) return;
  const int k0 = blockIdx.x * 64;
  const int off = (t < 51) ? t : (64 + t - 51);
  float s = 0.f;
  for (int k = k0; k < k0 + 64; ++k) s += p[k * 128 + off];
  atomicAdd(&st[(t < 51) ? t : (512 + t - 51)], s);
}

// ---------------------------------------------------------------------------
// Per-channel sum/sumsq over [B,C,HL], HL split NS ways; grid (C,B,NS)
// (kept for layers 9/10 only)
// ---------------------------------------------------------------------------
__global__ __launch_bounds__(256) void stats_kernel(
    const float* __restrict__ Y, float* __restrict__ st, int C, int HL,
    int NS) {
  const int c = blockIdx.x, b = blockIdx.y, z = blockIdx.z;
  const int slice = HL / NS;
  const float* p = Y + ((size_t)b * C + c) * HL + (size_t)z * slice;
  float s = 0.f, q = 0.f;
  for (int i = threadIdx.x; i < slice; i += 256) {
    float v = p[i];
    s += v;
    q += v * v;
  }
#pragma unroll
  for (int off = 32; off > 0; off >>= 1) {
    s += __shfl_down(s, off, 64);
    q += __shfl_down(q, off, 64);
  }
  __shared__ float ls[4], lq[4];
  const int wid = threadIdx.x >> 6, lane = threadIdx.x & 63;
  if (lane == 0) { ls[wid] = s; lq[wid] = q; }
  __syncthreads();
  if (threadIdx.x == 0) {
    atomicAdd(&st[c], ls[0] + ls[1] + ls[2] + ls[3]);
    atomicAdd(&st[512 + c], lq[0] + lq[1] + lq[2] + lq[3]);
  }
}

// ---------------------------------------------------------------------------
// reduce NS partial buffers: y[i] = sum_k p[k*stride + i]
// ---------------------------------------------------------------------------
__global__ __launch_bounds__(256) void reduce_parts_kernel(
    const float* __restrict__ p, float* __restrict__ y, int n, int stride,
    int ns) {
  int i = blockIdx.x * 256 + threadIdx.x;
  if (i >= n) return;
  float s = 0.f;
  for (int k = 0; k < ns; ++k) s += p[(size_t)k * stride + i];
  y[i] = s;
}

// ---------------------------------------------------------------------------
// Inline 8-slice parts stats: m/v from pp[k*1024 + c], pp[k*1024 + 512 + c]
// ---------------------------------------------------------------------------
__device__ inline void parts_bn(const float* __restrict__ pp, unsigned c,
                                float invN, const float* __restrict__ g,
                                const float* __restrict__ bb, float& sc,
                                float& bi) {
  float ssum = 0.f, sqs = 0.f;
#pragma unroll
  for (int k = 0; k < 8; ++k) {
    ssum += pp[k * 1024 + c];
    sqs += pp[k * 1024 + 512 + c];
  }
  float m = ssum * invN;
  float v = sqs * invN - m * m;
  sc = g[c] * rsqrtf(v + EPSBN);
  bi = bb[c] - m * sc;
}

// ---------------------------------------------------------------------------
// BN(train)+ReLU+pool4, fp32 out — parts stats (layer 8)
// ---------------------------------------------------------------------------
__global__ __launch_bounds__(256) void bnrelu_pool_parts_kernel(
    const float* __restrict__ Y, const float* __restrict__ pp,
    const float* __restrict__ g, const float* __restrict__ bb,
    float* __restrict__ Z, int C, int H, int Lin, float invN,
    unsigned int total) {
  unsigned int idx = blockIdx.x * 256u + threadIdx.x;
  if (idx >= total) return;
  const unsigned int Lo = (unsigned int)(Lin >> 2);
  unsigned int lo = idx % Lo;
  unsigned int r1 = idx / Lo;
  unsigned int h = r1 % (unsigned int)H;
  unsigned int r2 = r1 / (unsigned int)H;
  unsigned int c = r2 % (unsigned int)C;
  unsigned int b = r2 / (unsigned int)C;
  float sc, bi;
  parts_bn(pp, c, invN, g, bb, sc, bi);
  const float* p = Y + (((size_t)b * C + c) * H + h) * Lin + 4u * lo;
  float a0 = p[0] * sc + bi, a1 = p[1] * sc + bi;
  float a2 = p[2] * sc + bi, a3 = p[3] * sc + bi;
  float r = fmaxf(fmaxf(a0, a1), fmaxf(a2, a3));
  Z[idx] = fmaxf(r, 0.f);
}

// ---- BN+ReLU+pool4 bf16-out, parts stats (layers 3,5)
__global__ __launch_bounds__(256) void bnrelu_pool_bf16_parts_kernel(
    const float* __restrict__ Y, const float* __restrict__ pp,
    const float* __restrict__ g, const float* __restrict__ bb,
    unsigned short* __restrict__ Z, int C, int H, int Lin, float invN,
    unsigned int total) {
  unsigned int idx = blockIdx.x * 256u + threadIdx.x;
  if (idx >= total) return;
  const unsigned int Lo = (unsigned int)(Lin >> 2);
  unsigned int lo = idx % Lo;
  unsigned int r1 = idx / Lo;
  unsigned int h = r1 % (unsigned int)H;
  unsigned int r2 = r1 / (unsigned int)H;
  unsigned int c = r2 % (unsigned int)C;
  unsigned int b = r2 / (unsigned int)C;
  float sc, bi;
  parts_bn(pp, c, invN, g, bb, sc, bi);
  const float* p = Y + (((size_t)b * C + c) * H + h) * Lin + 4u * lo;
  float a0 = p[0] * sc + bi, a1 = p[1] * sc + bi;
  float a2 = p[2] * sc + bi, a3 = p[3] * sc + bi;
  float r = fmaxf(fmaxf(a0, a1), fmaxf(a2, a3));
  Z[idx] = f2bf(fmaxf(r, 0.f));
}

// ---- BN+ReLU+pool4 bf16-out, fp32 input, st stats (layer 1)
__global__ __launch_bounds__(256) void bnrelu_pool_bf16_kernel(
    const float* __restrict__ Y, const float* __restrict__ st,
    const float* __restrict__ g, const float* __restrict__ bb,
    unsigned short* __restrict__ Z, int C, int H, int Lin, float invN,
    unsigned int total) {
  unsigned int idx = blockIdx.x * 256u + threadIdx.x;
  if (idx >= total) return;
  const unsigned int Lo = (unsigned int)(Lin >> 2);
  unsigned int lo = idx % Lo;
  unsigned int r1 = idx / Lo;
  unsigned int h = r1 % (unsigned int)H;
  unsigned int r2 = r1 / (unsigned int)H;
  unsigned int c = r2 % (unsigned int)C;
  unsigned int b = r2 / (unsigned int)C;
  float m = st[c] * invN;
  float v = st[512 + c] * invN - m * m;
  float sc = g[c] * rsqrtf(v + EPSBN);
  float bi = bb[c] - m * sc;
  const float* p = Y + (((size_t)b * C + c) * H + h) * Lin + 4u * lo;
  float a0 = p[0] * sc + bi, a1 = p[1] * sc + bi;
  float a2 = p[2] * sc + bi, a3 = p[3] * sc + bi;
  float r = fmaxf(fmaxf(a0, a1), fmaxf(a2, a3));
  Z[idx] = f2bf(fmaxf(r, 0.f));
}

// ---------------------------------------------------------------------------
// BN(train)+ReLU elementwise, fp32 out (layer 9) — st stats
// ---------------------------------------------------------------------------
__global__ __launch_bounds__(256) void bnrelu_kernel(
    const float* __restrict__ Y, const float* __restrict__ st,
    const float* __restrict__ g, const float* __restrict__ bb,
    float* __restrict__ A, int C, int HL, float invN, unsigned int total) {
  unsigned int idx = blockIdx.x * 256u + threadIdx.x;
  if (idx >= total) return;
  unsigned int c = (idx / (unsigned int)HL) % (unsigned int)C;
  float m = st[c] * invN;
  float v = st[512 + c] * invN - m * m;
  float sc = g[c] * rsqrtf(v + EPSBN);
  float bi = bb[c] - m * sc;
  A[idx] = fmaxf(fmaf(Y[idx], sc, bi), 0.f);
}

// ---- BN+ReLU bf16-out, parts stats (layers 2,4,6,7)
__global__ __launch_bounds__(256) void bnrelu_bf16_parts_kernel(
    const float* __restrict__ Y, const float* __restrict__ pp,
    const float* __restrict__ g, const float* __restrict__ bb,
    unsigned short* __restrict__ A, int C, int HL, float invN,
    unsigned int total) {
  unsigned int idx = blockIdx.x * 256u + threadIdx.x;
  if (idx >= total) return;
  unsigned int c = (idx / (unsigned int)HL) % (unsigned int)C;
  float sc, bi;
  parts_bn(pp, c, invN, g, bb, sc, bi);
  A[idx] = f2bf(fmaxf(fmaf(Y[idx], sc, bi), 0.f));
}

// ---------------------------------------------------------------------------
// Pack fp32 weights -> per-s split bf16 packs with 2^-(s+i) folded.
// ---------------------------------------------------------------------------
__global__ __launch_bounds__(256) void pack_w2_kernel(
    const float* __restrict__ W, short* __restrict__ A, int Co, int KTOT,
    int KPAD, int COPAD, int NS, int nk3) {
  int idx = blockIdx.x * 256 + threadIdx.x;
  const int CK = COPAD * KPAD;
  if (idx >= NS * CK) return;
  int s = idx / CK;
  int rem = idx - s * CK;
  int co = rem / KPAD;
  int kk = rem - co * KPAD;
  float v = 0.f;
  if (co < Co && kk < KTOT) {
    int i = (kk % nk3) / 3;
    float scale = __uint_as_float((unsigned)(127 - (s + i)) << 23);
    v = W[co * KTOT + kk] * scale;
  }
  unsigned short hi = f2bf(v);
  unsigned short lo = f2bf(v - bf2f(hi));
  A[(size_t)s * 2 * CK + co * KPAD + kk] = (short)hi;
  A[(size_t)s * 2 * CK + CK + co * KPAD + kk] = (short)lo;
}

// ---------------------------------------------------------------------------
// gg_mfma5: bf16-input MFMA GConvGG + fused per-channel stats (DPP reduce
// per 16-lane quad-row, lc-sliced atomic parts).
// ---------------------------------------------------------------------------
template <int NKv, int LT>
__global__ __launch_bounds__(256) void gg_mfma5_kernel(
    const unsigned short* __restrict__ X, const short* __restrict__ Apk,
    float* __restrict__ Y, float* __restrict__ part, int Ci, int Co, int Hin,
    int L, int nL, int KTOT, int KPAD, int COPAD) {
  constexpr int T = LT / 16;
  constexpr int KO = 256 / LT;
  constexpr int RIT = 8 / KO;

  const int bx = blockIdx.x;
  const int lc = bx % nL;
  const int cog = bx / nL;
  const int s = blockIdx.y;
  const int b = blockIdx.z;
  const int Hout = Hin - NKv + 1;
  const int l0 = lc * LT;
  const int tid = threadIdx.x;
  const int lane = tid & 63;
  const int quad = lane >> 4;
  const int m0 = lane & 15;
  const int wv = tid >> 6;
  const int coBase = cog * 64 + wv * 16;

  __shared__ __align__(16) short Bh[LT * 72];
  __shared__ int roT[1024];
  __shared__ int shT[1024];
  __shared__ float sCh[2][64];

  for (int kk = tid; kk < KPAD; kk += 256) {
    int ro = 0, sh = -(1 << 30);
    if (kk < KTOT) {
      int ci = kk / (3 * NKv);
      int rem = kk - ci * (3 * NKv);
      int i = rem / 3;
      int k = rem - 3 * i;
      ro = (ci * Hin + s + i) * L;
      sh = (k - 1) * (1 << (s + i));
    }
    roT[kk] = ro;
    shT[kk] = sh;
  }
  __syncthreads();

  f32x4 acc[T];
#pragma unroll
  for (int t = 0; t < T; ++t) acc[t] = (f32x4){0.f, 0.f, 0.f, 0.f};

  const short* ApkS = Apk + (size_t)s * 2 * COPAD * KPAD;
  const short* arowH = ApkS + (size_t)(coBase + m0) * KPAD;
  const short* arowL = arowH + (size_t)COPAD * KPAD;
  const unsigned short* Xb = X + (size_t)b * Ci * Hin * L;

  const int lB = tid & (LT - 1);
  const int oc0 = tid / LT;
  const int nch = (KTOT + 63) >> 6;

  uint4 v0[RIT], v1[RIT], v2[RIT];
  auto gather = [&](int c0, uint4 (&pk)[RIT]) {
#pragma unroll
    for (int r = 0; r < RIT; ++r) {
      const int oct = oc0 + KO * r;
      const int kkb = (c0 << 6) + oct * 8;
      unsigned w[8];
#pragma unroll
      for (int j = 0; j < 8; ++j) {
        const int kk = kkb + j;
        const int pos = l0 + lB + shT[kk];
        const int posc = min(max(pos, 0), L - 1);
        unsigned u = (unsigned)Xb[roT[kk] + posc];
        w[j] = ((unsigned)pos < (unsigned)L) ? u : 0u;
      }
      pk[r].x = w[0] | (w[1] << 16);
      pk[r].y = w[2] | (w[3] << 16);
      pk[r].z = w[4] | (w[5] << 16);
      pk[r].w = w[6] | (w[7] << 16);
    }
  };

  gather(0, v0);
  if (nch > 1) gather(1, v1);
  for (int c0 = 0; c0 < nch; ++c0) {
#pragma unroll
    for (int r = 0; r < RIT; ++r)
      *(uint4*)(Bh + lB * 72 + (oc0 + KO * r) * 8) = v0[r];
    if (c0 + 2 < nch) gather(c0 + 2, v2);
    const int a0 = (c0 << 6) + quad * 8;
    short8v ah0 = *(const short8v*)(arowH + a0);
    short8v al0 = *(const short8v*)(arowL + a0);
    short8v ah1 = *(const short8v*)(arowH + a0 + 32);
    short8v al1 = *(const short8v*)(arowL + a0 + 32);
    __syncthreads();
#pragma unroll
    for (int t = 0; t < T; ++t) {
      const int l = m0 + 16 * t;
      short8v b0 = *(const short8v*)(Bh + l * 72 + quad * 8);
      short8v b1 = *(const short8v*)(Bh + l * 72 + 32 + quad * 8);
      acc[t] = __builtin_amdgcn_mfma_f32_16x16x32_bf16(ah0, b0, acc[t], 0, 0, 0);
      acc[t] = __builtin_amdgcn_mfma_f32_16x16x32_bf16(al0, b0, acc[t], 0, 0, 0);
      acc[t] = __builtin_amdgcn_mfma_f32_16x16x32_bf16(ah1, b1, acc[t], 0, 0, 0);
      acc[t] = __builtin_amdgcn_mfma_f32_16x16x32_bf16(al1, b1, acc[t], 0, 0, 0);
    }
    __syncthreads();
#pragma unroll
    for (int r = 0; r < RIT; ++r) {
      v0[r] = v1[r];
      v1[r] = v2[r];
    }
  }

#pragma unroll
  for (int reg = 0; reg < 4; ++reg) {
    const int co = coBase + quad * 4 + reg;
    float ss = 0.f, sq = 0.f;
    if (co < Co) {
      float* yp = Y + (((size_t)b * Co + co) * Hout + s) * L + l0;
#pragma unroll
      for (int t = 0; t < T; ++t) {
        float v = acc[t][reg];
        yp[m0 + 16 * t] = v;
        ss += v;
        sq = fmaf(v, v, sq);
      }
    }
    ss = dpp_radd<0x128>(ss);
    sq = dpp_radd<0x128>(sq);
    ss = dpp_radd<0x124>(ss);
    sq = dpp_radd<0x124>(sq);
    ss = dpp_radd<0x122>(ss);
    sq = dpp_radd<0x122>(sq);
    ss = dpp_radd<0x121>(ss);
    sq = dpp_radd<0x121>(sq);
    if (m0 == 0) {
      sCh[0][wv * 16 + quad * 4 + reg] = ss;
      sCh[1][wv * 16 + quad * 4 + reg] = sq;
    }
  }
  __syncthreads();
  if (tid < 64) {
    const int co = cog * 64 + tid;
    if (co < Co) {
      float* pp = part + (size_t)(lc & 7) * 1024;
      atomicAdd(&pp[co], sCh[0][tid]);
      atomicAdd(&pp[512 + co], sCh[1][tid]);
    }
  }
}

// ---------------------------------------------------------------------------
// gg_tail3: unrolled, atomic-free tail GConvGG (layers 9/10).
// ---------------------------------------------------------------------------
template <int NK, int L, int COSUB, int UN>
__global__ __launch_bounds__(256) void gg_tail3_kernel(
    const float* __restrict__ X, const float* __restrict__ W,
    float* __restrict__ Y, int Ci, int Co, int Hin, int NSPLIT, int ciPer,
    int partStride) {
  const int l = threadIdx.x % L;
  const int cs = threadIdx.x / L;
  const int co = blockIdx.x * COSUB + cs;
  const int s = blockIdx.y / NSPLIT;
  const int seg = blockIdx.y % NSPLIT;
  const int b = blockIdx.z;
  const int Hout = Hin - NK + 1;
  const int ciBeg = seg * ciPer;
  const int ciEnd = min(Ci, ciBeg + ciPer);

  float acc[NK];
#pragma unroll
  for (int i = 0; i < NK; ++i) acc[i] = 0.f;

  const float* wbase = W + (size_t)co * Ci * NK * 3;
  const float* xbase = X + ((size_t)b * Ci * Hin + s) * L;

  int ci = ciBeg;
  for (; ci + UN <= ciEnd; ci += UN) {
    float xv[UN][NK][3];
#pragma unroll
    for (int u = 0; u < UN; ++u) {
      const float* xr = xbase + (size_t)(ci + u) * (Hin * L);
#pragma unroll
      for (int i = 0; i < NK; ++i) {
        const int d = 1 << (s + i);
        const float* row = xr + i * L;
        xv[u][i][0] = (l >= d) ? row[l - d] : 0.f;
        xv[u][i][1] = row[l];
        xv[u][i][2] = (l + d < L) ? row[l + d] : 0.f;
      }
    }
#pragma unroll
    for (int u = 0; u < UN; ++u) {
      const float* wp = wbase + (ci + u) * (NK * 3);
#pragma unroll
      for (int i = 0; i < NK; ++i)
        acc[i] = fmaf(wp[3 * i], xv[u][i][0],
                      fmaf(wp[3 * i + 1], xv[u][i][1],
                           fmaf(wp[3 * i + 2], xv[u][i][2], acc[i])));
    }
  }
  for (; ci < ciEnd; ++ci) {
    const float* xr = xbase + (size_t)ci * (Hin * L);
    const float* wp = wbase + ci * (NK * 3);
#pragma unroll
    for (int i = 0; i < NK; ++i) {
      const int d = 1 << (s + i);
      const float* row = xr + i * L;
      float xm = (l >= d) ? row[l - d] : 0.f;
      float xc = row[l];
      float xp = (l + d < L) ? row[l + d] : 0.f;
      acc[i] = fmaf(wp[3 * i], xm,
                    fmaf(wp[3 * i + 1], xc, fmaf(wp[3 * i + 2], xp, acc[i])));
    }
  }
  float out = 0.f;
#pragma unroll
  for (int i = 0; i < NK; ++i) {
    float invd = __uint_as_float((unsigned)(127 - (s + i)) << 23);
    out = fmaf(acc[i], invd, out);
  }
  Y[(size_t)seg * partStride + (((size_t)b * Co + co) * Hout + s) * L + l] =
      out;
}

// ---------------------------------------------------------------------------
// Final: bn10+relu, mean over L, classifier
// ---------------------------------------------------------------------------
__global__ __launch_bounds__(256) void final_kernel(
    const float* __restrict__ Y, const float* __restrict__ st,
    const float* __restrict__ g, const float* __restrict__ bb,
    const float* __restrict__ w11, float* __restrict__ out) {
  const int b = blockIdx.x;
  const int tid = threadIdx.x;
  __shared__ float tch[408];
  for (int c = tid; c < 408; c += 256) {
    float m = st[c] * (1.f / 256.f);
    float v = st[512 + c] * (1.f / 256.f) - m * m;
    float sc = g[c] * rsqrtf(v + EPSBN);
    float bi = bb[c] - m * sc;
    const float* p = Y + ((size_t)b * 408 + c) * 32;
    float ssum = 0.f;
#pragma unroll
    for (int l = 0; l < 32; ++l) ssum += fmaxf(p[l] * sc + bi, 0.f);
    tch[c] = ssum * (1.f / 32.f);
  }
  __syncthreads();
  if (tid < 10) {
    float ssum = 0.f;
    for (int c = 0; c < 408; ++c) ssum += w11[tid * 408 + c] * tch[c];
    out[b * 10 + tid] = ssum;
  }
}

// ---------------------------------------------------------------------------
extern "C" void kernel_launch(void* const* d_in, const int* in_sizes, int n_in,
                              void* d_out, int out_size, void* d_ws,
                              size_t ws_size, hipStream_t stream) {
  const float* x = (const float*)d_in[0];
  const float* w1 = (const float*)d_in[1];
  const float* w2 = (const float*)d_in[2];
  const float* w3 = (const float*)d_in[3];
  const float* w4 = (const float*)d_in[4];
  const float* w5 = (const float*)d_in[5];
  const float* w6 = (const float*)d_in[6];
  const float* w7 = (const float*)d_in[7];
  const float* w8 = (const float*)d_in[8];
  const float* w9 = (const float*)d_in[9];
  const float* w10 = (const float*)d_in[10];
  const float* w11 = (const float*)d_in[11];
  const float* gg[11];
  const float* bbv[11];
  for (int i = 1; i <= 10; ++i) {
    gg[i] = (const float*)d_in[12 + 2 * (i - 1)];
    bbv[i] = (const float*)d_in[12 + 2 * (i - 1) + 1];
  }

  float* ws = (float*)d_ws;
  const size_t AR0 = 0;
  const size_t AR1 = 30081024;
  const size_t STATS = 38900000;
  float* y1 = ws + AR0;
  short* apk1 = (short*)(ws + AR1 + 460800);              // 110592 shorts
  uint2* xpair = (uint2*)(ws + AR1 + 520000);             // 4110336 uint2
  float* part1 = ws + AR1 + 8740672;                      // 512*128 fp32
  unsigned short* z1b = (unsigned short*)(ws + AR1);
  unsigned short* a3b = (unsigned short*)(ws + AR1);
  unsigned short* z3b = (unsigned short*)(ws + AR1);
  unsigned short* a5b = (unsigned short*)(ws + AR1 + 1500000);
  unsigned short* z5b = (unsigned short*)(ws + AR1);          // 522240 sh
  unsigned short* a6b = (unsigned short*)(ws + AR1 + 522240); // 626688 sh
  unsigned short* a7b = (unsigned short*)(ws + AR1 + 1148928);
  float* z8 = ws + AR1;
  float* a9 = ws + AR1 + 1775616;
  float* part9 = ws + AR1 + 1900000;   // 4 * 104448
  float* part10 = ws + AR1 + 2400000;  // 4 * 104448
  float* y2 = ws + AR0;
  float* y3 = ws + AR0 + 5849088;
  float* y4 = ws + AR0;
  float* y5 = ws + AR0 + 2088960;
  float* y6 = ws + AR0;
  float* y7 = ws + AR0 + 626688;
  float* y8 = ws + AR0 + 1253376;
  float* y9 = ws + AR0;
  float* y10 = ws + AR0 + 104448;
  short* apk2 = (short*)(ws + 12000000);
  short* apk3 = apk2 + 7 * 2 * 64 * 512;
  short* apk4 = apk3 + 7 * 2 * 64 * 192;
  short* apk5 = apk4 + 5 * 2 * 128 * 512;
  short* apk6 = apk5 + 5 * 2 * 128 * 320;   // 3*2*256*960 shorts
  short* apk7 = apk6 + 3 * 2 * 256 * 960;   // 3*2*256*640
  short* apk8 = apk7 + 3 * 2 * 256 * 640;   // 3*2*256*640
  float* st[11];
  for (int i = 1; i <= 10; ++i) st[i] = ws + STATS + (size_t)(i - 1) * 1024;
  // per-layer 8-slice stats parts for layers 2..8 (8*1024 floats each)
  float* partg = ws + STATS + 10240;
  float* part2 = partg;
  float* part3 = partg + 8192;
  float* part4 = partg + 2 * 8192;
  float* part5 = partg + 3 * 8192;
  float* part6 = partg + 4 * 8192;
  float* part7 = partg + 5 * 8192;
  float* part8 = partg + 6 * 8192;

  hipMemsetAsync((void*)(ws + STATS), 0, 10 * 1024 * sizeof(float), stream);
  hipMemsetAsync((void*)part1, 0, 512 * 128 * sizeof(float), stream);
  hipMemsetAsync((void*)partg, 0, 7 * 8192 * sizeof(float), stream);

  // ---- interleaved per-s pair array (pad_x folded in), pack w1, MFMA lift
  pad_pair_kernel<<<dim3((PROW + 255) / 256, 72), 256, 0, stream>>>(x, xpair);
  pack_w1_kernel<<<(9 * 64 * 96 + 255) / 256, 256, 0, stream>>>(w1, apk1);
  lift_mfma_kernel<<<dim3(512, 9, 8), 256, 0, stream>>>(xpair, apk1, y1,
                                                        part1);
  reduce_stats1_kernel<<<8, 128, 0, stream>>>(part1, st[1]);
  {
    unsigned int tot = 8u * 51 * 9 * 2048;
    bnrelu_pool_bf16_kernel<<<(tot + 255) / 256, 256, 0, stream>>>(
        y1, st[1], gg[1], bbv[1], z1b, 51, 9, 8192, 1.f / 589824.f, tot);
  }
  // ---- per-s weight packs
  pack_w2_kernel<<<(7 * 64 * 512 + 255) / 256, 256, 0, stream>>>(
      w2, apk2, 51, 459, 512, 64, 7, 9);
  pack_w2_kernel<<<(7 * 64 * 192 + 255) / 256, 256, 0, stream>>>(
      w3, apk3, 51, 153, 192, 64, 7, 3);
  pack_w2_kernel<<<(5 * 128 * 512 + 255) / 256, 256, 0, stream>>>(
      w4, apk4, 102, 459, 512, 128, 5, 9);
  pack_w2_kernel<<<(5 * 128 * 320 + 255) / 256, 256, 0, stream>>>(
      w5, apk5, 102, 306, 320, 128, 5, 3);
  pack_w2_kernel<<<(3 * 256 * 960 + 255) / 256, 256, 0, stream>>>(
      w6, apk6, 204, 918, 960, 256, 3, 9);
  pack_w2_kernel<<<(3 * 256 * 640 + 255) / 256, 256, 0, stream>>>(
      w7, apk7, 204, 612, 640, 256, 3, 3);
  pack_w2_kernel<<<(3 * 256 * 640 + 255) / 256, 256, 0, stream>>>(
      w8, apk8, 204, 612, 640, 256, 3, 3);
  // ---- gg2: 51->51, H 9->7, L=2048 (fused stats)
  gg_mfma5_kernel<3, 64><<<dim3(32, 7, 8), 256, 0, stream>>>(
      z1b, apk2, y2, part2, 51, 51, 9, 2048, 32, 459, 512, 64);
  {
    unsigned int tot = 8u * 51 * 7 * 2048;
    bnrelu_bf16_parts_kernel<<<(tot + 255) / 256, 256, 0, stream>>>(
        y2, part2, gg[2], bbv[2], a3b, 51, 7 * 2048, 1.f / 114688.f, tot);
  }
  // ---- gg3: 51->51, H7, L=2048 (fused stats)
  gg_mfma5_kernel<1, 64><<<dim3(32, 7, 8), 256, 0, stream>>>(
      a3b, apk3, y3, part3, 51, 51, 7, 2048, 32, 153, 192, 64);
  {
    unsigned int tot = 8u * 51 * 7 * 512;
    bnrelu_pool_bf16_parts_kernel<<<(tot + 255) / 256, 256, 0, stream>>>(
        y3, part3, gg[3], bbv[3], z3b, 51, 7, 2048, 1.f / 114688.f, tot);
  }
  // ---- gg4: 51->102, H 7->5, L=512 (fused stats)
  gg_mfma5_kernel<3, 32><<<dim3(32, 5, 8), 256, 0, stream>>>(
      z3b, apk4, y4, part4, 51, 102, 7, 512, 16, 459, 512, 128);
  {
    unsigned int tot = 8u * 102 * 5 * 512;
    bnrelu_bf16_parts_kernel<<<(tot + 255) / 256, 256, 0, stream>>>(
        y4, part4, gg[4], bbv[4], a5b, 102, 5 * 512, 1.f / 20480.f, tot);
  }
  // ---- gg5: 102->102, H5, L=512 (fused stats)
  gg_mfma5_kernel<1, 32><<<dim3(32, 5, 8), 256, 0, stream>>>(
      a5b, apk5, y5, part5, 102, 102, 5, 512, 16, 306, 320, 128);
  {
    unsigned int tot = 8u * 102 * 5 * 128;
    bnrelu_pool_bf16_parts_kernel<<<(tot + 255) / 256, 256, 0, stream>>>(
        y5, part5, gg[5], bbv[5], z5b, 102, 5, 512, 1.f / 20480.f, tot);
  }
  // ---- gg6: 102->204, H 5->3, L=128 — MFMA + fused stats
  gg_mfma5_kernel<3, 32><<<dim3(16, 3, 8), 256, 0, stream>>>(
      z5b, apk6, y6, part6, 102, 204, 5, 128, 4, 918, 960, 256);
  {
    unsigned int tot = 8u * 204 * 3 * 128;
    bnrelu_bf16_parts_kernel<<<(tot + 255) / 256, 256, 0, stream>>>(
        y6, part6, gg[6], bbv[6], a6b, 204, 3 * 128, 1.f / 3072.f, tot);
  }
  // ---- gg7: 204->204, H3, L=128 — MFMA + fused stats
  gg_mfma5_kernel<1, 32><<<dim3(16, 3, 8), 256, 0, stream>>>(
      a6b, apk7, y7, part7, 204, 204, 3, 128, 4, 612, 640, 256);
  {
    unsigned int tot = 8u * 204 * 3 * 128;
    bnrelu_bf16_parts_kernel<<<(tot + 255) / 256, 256, 0, stream>>>(
        y7, part7, gg[7], bbv[7], a7b, 204, 3 * 128, 1.f / 3072.f, tot);
  }
  // ---- gg8: 204->204, H3, L=128 — MFMA + fused stats
  gg_mfma5_kernel<1, 32><<<dim3(16, 3, 8), 256, 0, stream>>>(
      a7b, apk8, y8, part8, 204, 204, 3, 128, 4, 612, 640, 256);
  {
    unsigned int tot = 8u * 204 * 3 * 32;
    bnrelu_pool_parts_kernel<<<(tot + 255) / 256, 256, 0, stream>>>(
        y8, part8, gg[8], bbv[8], z8, 204, 3, 128, 1.f / 3072.f, tot);
  }
  // ---- gg9: 204->408, H 3->1, L=32 (K-split x4 into partials, reduce)
  gg_tail3_kernel<3, 32, 8, 2><<<dim3(51, 4, 8), 256, 0, stream>>>(
      z8, w9, part9, 204, 408, 3, 4, 51, 104448);
  reduce_parts_kernel<<<(104448 + 255) / 256, 256, 0, stream>>>(
      part9, y9, 104448, 104448, 4);
  stats_kernel<<<dim3(408, 8, 1), 256, 0, stream>>>(y9, st[9], 408, 32, 1);
  {
    unsigned int tot = 8u * 408 * 32;
    bnrelu_kernel<<<(tot + 255) / 256, 256, 0, stream>>>(
        y9, st[9], gg[9], bbv[9], a9, 408, 32, 1.f / 256.f, tot);
  }
  // ---- gg10: 408->408, H1, L=32 (K-split x4 into partials, reduce)
  gg_tail3_kernel<1, 32, 8, 8><<<dim3(51, 4, 8), 256, 0, stream>>>(
      a9, w10, part10, 408, 408, 1, 4, 102, 104448);
  reduce_parts_kernel<<<(104448 + 255) / 256, 256, 0, stream>>>(
      part10, y10, 104448, 104448, 4);
  stats_kernel<<<dim3(408, 8, 1), 256, 0, stream>>>(y10, st[10], 408, 32, 1);
  // ---- final
  final_kernel<<<dim3(8), 256, 0, stream>>>(y10, st[10], gg[10], bbv[10], w11,
                                            (float*)d_out);
}

// Round 12
// 606.166 us; speedup vs baseline: 1.0072x; 1.0072x over previous
//
#include <hip/hip_runtime.h>
#include <hip/hip_bf16.h>

#define EPSBN 2e-5f

typedef __attribute__((ext_vector_type(8))) short short8v;
typedef __attribute__((ext_vector_type(4))) float f32x4;

__device__ inline unsigned short f2bf(float f) {
  unsigned u = __float_as_uint(f);
  unsigned r = (u + 0x7FFFu + ((u >> 16) & 1u)) >> 16;
  return (unsigned short)r;
}
__device__ inline float bf2f(unsigned short h) {
  return __uint_as_float(((unsigned)h) << 16);
}

// DPP row-rotate float add: v += rotate_within_16(v, N). VALU pipe, not LDS.
template <int CTRL>
__device__ inline float dpp_radd(float v) {
  int r = __builtin_amdgcn_update_dpp(0, __float_as_int(v), CTRL, 0xf, 0xf,
                                      true);
  return v + __int_as_float(r);
}

// ---------------------------------------------------------------------------
// Per-scale pair-packed B source (separate H/L arrays — R11's interleaved
// uint2 staging LOST memory-level parallelism in lift, 124.8->137 µs).
// pad_x folded in: split computed directly from x (R11-proven, ~9 µs).
//   xpH[(s*8+b)*PROW + i] = hi(x[i]) | hi(x[i+d])<<16
//   xpL[...]              = lo(x[i]) | lo(x[i+d])<<16
// ---------------------------------------------------------------------------
constexpr int XPADL = 9984;
constexpr int XPADR = 14336;
constexpr int PROW = XPADL + 32768 + XPADR;  // 57088

__global__ __launch_bounds__(256) void pad_pair_kernel(
    const float* __restrict__ x, unsigned* __restrict__ xpH,
    unsigned* __restrict__ xpL) {
  const int i = blockIdx.x * 256 + threadIdx.x;
  if (i >= PROW) return;
  const int sb = blockIdx.y;  // s*8 + b
  const int s = sb >> 3;
  const int b = sb & 7;
  const int d = 1 << s;
  const int pos0 = i - XPADL;
  const int pos1 = pos0 + d;
  float v0 = (pos0 >= 0 && pos0 < 32768) ? x[b * 32768 + pos0] : 0.f;
  float v1 = (pos1 >= 0 && pos1 < 32768) ? x[b * 32768 + pos1] : 0.f;
  unsigned u0 = __float_as_uint(v0);
  unsigned h0 = u0 >> 16;
  unsigned lo0 =
      __float_as_uint(v0 - __uint_as_float(u0 & 0xffff0000u)) >> 16;
  unsigned u1 = __float_as_uint(v1);
  unsigned h1 = u1 >> 16;
  unsigned lo1 =
      __float_as_uint(v1 - __uint_as_float(u1 & 0xffff0000u)) >> 16;
  size_t o = (size_t)sb * PROW + i;
  xpH[o] = h0 | (h1 << 16);
  xpL[o] = lo0 | (lo1 << 16);
}

// ---------------------------------------------------------------------------
// Pack w1 [51][79] -> per-s split bf16 (1/2^s folded), [s][hi/lo][64][96]
// ---------------------------------------------------------------------------
__global__ __launch_bounds__(256) void pack_w1_kernel(
    const float* __restrict__ W, short* __restrict__ A) {
  int idx = blockIdx.x * 256 + threadIdx.x;
  if (idx >= 9 * 64 * 96) return;
  int s = idx / (64 * 96);
  int rem = idx - s * 64 * 96;
  int co = rem / 96;
  int k = rem - co * 96;
  float v = 0.f;
  if (co < 51 && k < 79)
    v = W[co * 79 + k] * __uint_as_float((unsigned)(127 - s) << 23);
  unsigned short hi = f2bf(v);
  unsigned short lo = f2bf(v - bf2f(hi));
  A[(size_t)s * 2 * 64 * 96 + co * 96 + k] = (short)hi;
  A[(size_t)s * 2 * 64 * 96 + 64 * 96 + co * 96 + k] = (short)lo;
}

// ---------------------------------------------------------------------------
// lift_mfma: MFMA GEMM + fused pool4 + DPP stats reduce. y1 fp32 (bf16 y1
// broke absmax in R9). Staging = R10's 24 coalesced dword loads. sCh is
// ALIASED into Bh (dead after the MFMA loop; extra barrier separates the
// last LDS read from the aliased write) -> LDS 27136->26624 B -> 6 blocks/CU
// instead of 5 (+20% occupancy to hide staging latency).
// ---------------------------------------------------------------------------
__global__ __launch_bounds__(256) void lift_mfma_kernel(
    const unsigned* __restrict__ xpH, const unsigned* __restrict__ xpL,
    const short* __restrict__ Apk1, float* __restrict__ y1,
    float* __restrict__ part1) {
  constexpr int P = 104;
  const int bid = blockIdx.x;
  const int lc = (bid & 7) * 64 + (bid >> 3);  // 512 = 8*64, bijective
  const int s = blockIdx.y;
  const int b = blockIdx.z;
  const int d = 1 << s;
  const int l0 = lc * 64;
  const int tid = threadIdx.x;
  const int lane = tid & 63;
  const int quad = lane >> 4;
  const int n0 = lane & 15;
  const int wv = tid >> 6;
  const int coBase = wv * 16;

  __shared__ __align__(16) short Bh[64 * P];
  __shared__ __align__(16) short Bl[64 * P];
  float* sC = (float*)Bh;  // aliased stats scratch (128 floats)

  const int nB = tid & 63;
  const int rowW = ((nB & 3) << 4) | (nB >> 2);  // LDS row permutation
  const int swzW = (nB & 3) << 3;                // write slot XOR (shorts)
  const int ogu = __builtin_amdgcn_readfirstlane(tid >> 6);
  const unsigned* xqH = xpH + (size_t)(s * 8 + b) * PROW + XPADL + l0;
  const unsigned* xqL = xpL + (size_t)(s * 8 + b) * PROW + XPADL + l0;

#pragma unroll
  for (int r = 0; r < 3; ++r) {
    const int kb = (ogu + 4 * r) * 8;
    const int base = (kb - 39) * d;
    uint4 ph, pl;
    ph.x = xqH[base + nB];
    ph.y = xqH[base + 2 * d + nB];
    ph.z = xqH[base + 4 * d + nB];
    ph.w = xqH[base + 6 * d + nB];
    pl.x = xqL[base + nB];
    pl.y = xqL[base + 2 * d + nB];
    pl.z = xqL[base + 4 * d + nB];
    pl.w = xqL[base + 6 * d + nB];
    *(uint4*)(Bh + rowW * P + (kb ^ swzW)) = ph;
    *(uint4*)(Bl + rowW * P + (kb ^ swzW)) = pl;
  }

  const short* ApkS = Apk1 + (size_t)s * 2 * 64 * 96;
  const short* arowH = ApkS + (coBase + n0) * 96;
  const short* arowL = arowH + 64 * 96;

  __syncthreads();

  f32x4 acc[4];
#pragma unroll
  for (int t = 0; t < 4; ++t) acc[t] = (f32x4){0.f, 0.f, 0.f, 0.f};

#pragma unroll
  for (int ks = 0; ks < 3; ++ks) {
    short8v ah = *(const short8v*)(arowH + ks * 32 + quad * 8);
    short8v al = *(const short8v*)(arowL + ks * 32 + quad * 8);
#pragma unroll
    for (int t = 0; t < 4; ++t) {
      const int n = n0 + 16 * t;
      const int off = (ks * 32 + quad * 8) ^ (t << 3);
      short8v bh = *(const short8v*)(Bh + n * P + off);
      short8v bl = *(const short8v*)(Bl + n * P + off);
      acc[t] = __builtin_amdgcn_mfma_f32_16x16x32_bf16(ah, bh, acc[t], 0, 0, 0);
      acc[t] = __builtin_amdgcn_mfma_f32_16x16x32_bf16(ah, bl, acc[t], 0, 0, 0);
      acc[t] = __builtin_amdgcn_mfma_f32_16x16x32_bf16(al, bh, acc[t], 0, 0, 0);
    }
  }

  // All LDS reads of Bh/Bl done -> safe to alias sC onto Bh after barrier.
  __syncthreads();

#pragma unroll
  for (int reg = 0; reg < 4; ++reg) {
    const int co = coBase + quad * 4 + reg;
    float po = fmaxf(fmaxf(acc[0][reg], acc[1][reg]),
                     fmaxf(acc[2][reg], acc[3][reg]));
    const bool valid = (co < 51);
    if (valid) {
      y1[(((size_t)b * 51 + co) * 9 + s) * 8192 + (l0 >> 2) + n0] = po;
    }
    float us = valid ? po : 0.f;
    float sq = us * us;
    us = dpp_radd<0x128>(us);
    sq = dpp_radd<0x128>(sq);
    us = dpp_radd<0x124>(us);
    sq = dpp_radd<0x124>(sq);
    us = dpp_radd<0x122>(us);
    sq = dpp_radd<0x122>(sq);
    us = dpp_radd<0x121>(us);
    sq = dpp_radd<0x121>(sq);
    if (n0 == 0) {
      sC[co] = us;
      sC[64 + co] = sq;
    }
  }
  __syncthreads();
  if (tid < 51) {
    float* pp = part1 + (size_t)lc * 128;
    atomicAdd(&pp[tid], sC[tid]);
    atomicAdd(&pp[64 + tid], sC[64 + tid]);
  }
}

// ---------------------------------------------------------------------------
// Reduce the 512 lc-sliced stats partials into st.
// ---------------------------------------------------------------------------
__global__ __launch_bounds__(128) void reduce_stats1_kernel(
    const float* __restrict__ p, float* __restrict__ st) {
  const int t = threadIdx.x;
  if (t >= 102) return;
  const int k0 = blockIdx.x * 64;
  const int off = (t < 51) ? t : (64 + t - 51);
  float s = 0.f;
  for (int k = k0; k < k0 + 64; ++k) s += p[k * 128 + off];
  atomicAdd(&st[(t < 51) ? t : (512 + t - 51)], s);
}

// ---------------------------------------------------------------------------
// Per-channel sum/sumsq over [B,C,HL], HL split NS ways; grid (C,B,NS)
// (kept for layers 9/10 only)
// ---------------------------------------------------------------------------
__global__ __launch_bounds__(256) void stats_kernel(
    const float* __restrict__ Y, float* __restrict__ st, int C, int HL,
    int NS) {
  const int c = blockIdx.x, b = blockIdx.y, z = blockIdx.z;
  const int slice = HL / NS;
  const float* p = Y + ((size_t)b * C + c) * HL + (size_t)z * slice;
  float s = 0.f, q = 0.f;
  for (int i = threadIdx.x; i < slice; i += 256) {
    float v = p[i];
    s += v;
    q += v * v;
  }
#pragma unroll
  for (int off = 32; off > 0; off >>= 1) {
    s += __shfl_down(s, off, 64);
    q += __shfl_down(q, off, 64);
  }
  __shared__ float ls[4], lq[4];
  const int wid = threadIdx.x >> 6, lane = threadIdx.x & 63;
  if (lane == 0) { ls[wid] = s; lq[wid] = q; }
  __syncthreads();
  if (threadIdx.x == 0) {
    atomicAdd(&st[c], ls[0] + ls[1] + ls[2] + ls[3]);
    atomicAdd(&st[512 + c], lq[0] + lq[1] + lq[2] + lq[3]);
  }
}

// ---------------------------------------------------------------------------
// reduce NS partial buffers: y[i] = sum_k p[k*stride + i]
// ---------------------------------------------------------------------------
__global__ __launch_bounds__(256) void reduce_parts_kernel(
    const float* __restrict__ p, float* __restrict__ y, int n, int stride,
    int ns) {
  int i = blockIdx.x * 256 + threadIdx.x;
  if (i >= n) return;
  float s = 0.f;
  for (int k = 0; k < ns; ++k) s += p[(size_t)k * stride + i];
  y[i] = s;
}

// ---------------------------------------------------------------------------
// Inline 8-slice parts stats: m/v from pp[k*1024 + c], pp[k*1024 + 512 + c]
// ---------------------------------------------------------------------------
__device__ inline void parts_bn(const float* __restrict__ pp, unsigned c,
                                float invN, const float* __restrict__ g,
                                const float* __restrict__ bb, float& sc,
                                float& bi) {
  float ssum = 0.f, sqs = 0.f;
#pragma unroll
  for (int k = 0; k < 8; ++k) {
    ssum += pp[k * 1024 + c];
    sqs += pp[k * 1024 + 512 + c];
  }
  float m = ssum * invN;
  float v = sqs * invN - m * m;
  sc = g[c] * rsqrtf(v + EPSBN);
  bi = bb[c] - m * sc;
}

// ---------------------------------------------------------------------------
// BN(train)+ReLU+pool4, fp32 out — parts stats (layer 8)
// ---------------------------------------------------------------------------
__global__ __launch_bounds__(256) void bnrelu_pool_parts_kernel(
    const float* __restrict__ Y, const float* __restrict__ pp,
    const float* __restrict__ g, const float* __restrict__ bb,
    float* __restrict__ Z, int C, int H, int Lin, float invN,
    unsigned int total) {
  unsigned int idx = blockIdx.x * 256u + threadIdx.x;
  if (idx >= total) return;
  const unsigned int Lo = (unsigned int)(Lin >> 2);
  unsigned int lo = idx % Lo;
  unsigned int r1 = idx / Lo;
  unsigned int h = r1 % (unsigned int)H;
  unsigned int r2 = r1 / (unsigned int)H;
  unsigned int c = r2 % (unsigned int)C;
  unsigned int b = r2 / (unsigned int)C;
  float sc, bi;
  parts_bn(pp, c, invN, g, bb, sc, bi);
  const float* p = Y + (((size_t)b * C + c) * H + h) * Lin + 4u * lo;
  float a0 = p[0] * sc + bi, a1 = p[1] * sc + bi;
  float a2 = p[2] * sc + bi, a3 = p[3] * sc + bi;
  float r = fmaxf(fmaxf(a0, a1), fmaxf(a2, a3));
  Z[idx] = fmaxf(r, 0.f);
}

// ---- BN+ReLU+pool4 bf16-out, parts stats (layers 3,5)
__global__ __launch_bounds__(256) void bnrelu_pool_bf16_parts_kernel(
    const float* __restrict__ Y, const float* __restrict__ pp,
    const float* __restrict__ g, const float* __restrict__ bb,
    unsigned short* __restrict__ Z, int C, int H, int Lin, float invN,
    unsigned int total) {
  unsigned int idx = blockIdx.x * 256u + threadIdx.x;
  if (idx >= total) return;
  const unsigned int Lo = (unsigned int)(Lin >> 2);
  unsigned int lo = idx % Lo;
  unsigned int r1 = idx / Lo;
  unsigned int h = r1 % (unsigned int)H;
  unsigned int r2 = r1 / (unsigned int)H;
  unsigned int c = r2 % (unsigned int)C;
  unsigned int b = r2 / (unsigned int)C;
  float sc, bi;
  parts_bn(pp, c, invN, g, bb, sc, bi);
  const float* p = Y + (((size_t)b * C + c) * H + h) * Lin + 4u * lo;
  float a0 = p[0] * sc + bi, a1 = p[1] * sc + bi;
  float a2 = p[2] * sc + bi, a3 = p[3] * sc + bi;
  float r = fmaxf(fmaxf(a0, a1), fmaxf(a2, a3));
  Z[idx] = f2bf(fmaxf(r, 0.f));
}

// ---- BN+ReLU+pool4 bf16-out, fp32 input, st stats (layer 1)
__global__ __launch_bounds__(256) void bnrelu_pool_bf16_kernel(
    const float* __restrict__ Y, const float* __restrict__ st,
    const float* __restrict__ g, const float* __restrict__ bb,
    unsigned short* __restrict__ Z, int C, int H, int Lin, float invN,
    unsigned int total) {
  unsigned int idx = blockIdx.x * 256u + threadIdx.x;
  if (idx >= total) return;
  const unsigned int Lo = (unsigned int)(Lin >> 2);
  unsigned int lo = idx % Lo;
  unsigned int r1 = idx / Lo;
  unsigned int h = r1 % (unsigned int)H;
  unsigned int r2 = r1 / (unsigned int)H;
  unsigned int c = r2 % (unsigned int)C;
  unsigned int b = r2 / (unsigned int)C;
  float m = st[c] * invN;
  float v = st[512 + c] * invN - m * m;
  float sc = g[c] * rsqrtf(v + EPSBN);
  float bi = bb[c] - m * sc;
  const float* p = Y + (((size_t)b * C + c) * H + h) * Lin + 4u * lo;
  float a0 = p[0] * sc + bi, a1 = p[1] * sc + bi;
  float a2 = p[2] * sc + bi, a3 = p[3] * sc + bi;
  float r = fmaxf(fmaxf(a0, a1), fmaxf(a2, a3));
  Z[idx] = f2bf(fmaxf(r, 0.f));
}

// ---------------------------------------------------------------------------
// BN(train)+ReLU elementwise, fp32 out (layer 9) — st stats
// ---------------------------------------------------------------------------
__global__ __launch_bounds__(256) void bnrelu_kernel(
    const float* __restrict__ Y, const float* __restrict__ st,
    const float* __restrict__ g, const float* __restrict__ bb,
    float* __restrict__ A, int C, int HL, float invN, unsigned int total) {
  unsigned int idx = blockIdx.x * 256u + threadIdx.x;
  if (idx >= total) return;
  unsigned int c = (idx / (unsigned int)HL) % (unsigned int)C;
  float m = st[c] * invN;
  float v = st[512 + c] * invN - m * m;
  float sc = g[c] * rsqrtf(v + EPSBN);
  float bi = bb[c] - m * sc;
  A[idx] = fmaxf(fmaf(Y[idx], sc, bi), 0.f);
}

// ---- BN+ReLU bf16-out, parts stats (layers 2,4,6,7)
__global__ __launch_bounds__(256) void bnrelu_bf16_parts_kernel(
    const float* __restrict__ Y, const float* __restrict__ pp,
    const float* __restrict__ g, const float* __restrict__ bb,
    unsigned short* __restrict__ A, int C, int HL, float invN,
    unsigned int total) {
  unsigned int idx = blockIdx.x * 256u + threadIdx.x;
  if (idx >= total) return;
  unsigned int c = (idx / (unsigned int)HL) % (unsigned int)C;
  float sc, bi;
  parts_bn(pp, c, invN, g, bb, sc, bi);
  A[idx] = f2bf(fmaxf(fmaf(Y[idx], sc, bi), 0.f));
}

// ---------------------------------------------------------------------------
// Pack fp32 weights -> per-s split bf16 packs with 2^-(s+i) folded.
// ---------------------------------------------------------------------------
__global__ __launch_bounds__(256) void pack_w2_kernel(
    const float* __restrict__ W, short* __restrict__ A, int Co, int KTOT,
    int KPAD, int COPAD, int NS, int nk3) {
  int idx = blockIdx.x * 256 + threadIdx.x;
  const int CK = COPAD * KPAD;
  if (idx >= NS * CK) return;
  int s = idx / CK;
  int rem = idx - s * CK;
  int co = rem / KPAD;
  int kk = rem - co * KPAD;
  float v = 0.f;
  if (co < Co && kk < KTOT) {
    int i = (kk % nk3) / 3;
    float scale = __uint_as_float((unsigned)(127 - (s + i)) << 23);
    v = W[co * KTOT + kk] * scale;
  }
  unsigned short hi = f2bf(v);
  unsigned short lo = f2bf(v - bf2f(hi));
  A[(size_t)s * 2 * CK + co * KPAD + kk] = (short)hi;
  A[(size_t)s * 2 * CK + CK + co * KPAD + kk] = (short)lo;
}

// ---------------------------------------------------------------------------
// gg_mfma5: bf16-input MFMA GConvGG + fused per-channel stats (DPP reduce
// per 16-lane quad-row, lc-sliced atomic parts).
// ---------------------------------------------------------------------------
template <int NKv, int LT>
__global__ __launch_bounds__(256) void gg_mfma5_kernel(
    const unsigned short* __restrict__ X, const short* __restrict__ Apk,
    float* __restrict__ Y, float* __restrict__ part, int Ci, int Co, int Hin,
    int L, int nL, int KTOT, int KPAD, int COPAD) {
  constexpr int T = LT / 16;
  constexpr int KO = 256 / LT;
  constexpr int RIT = 8 / KO;

  const int bx = blockIdx.x;
  const int lc = bx % nL;
  const int cog = bx / nL;
  const int s = blockIdx.y;
  const int b = blockIdx.z;
  const int Hout = Hin - NKv + 1;
  const int l0 = lc * LT;
  const int tid = threadIdx.x;
  const int lane = tid & 63;
  const int quad = lane >> 4;
  const int m0 = lane & 15;
  const int wv = tid >> 6;
  const int coBase = cog * 64 + wv * 16;

  __shared__ __align__(16) short Bh[LT * 72];
  __shared__ int roT[1024];
  __shared__ int shT[1024];
  __shared__ float sCh[2][64];

  for (int kk = tid; kk < KPAD; kk += 256) {
    int ro = 0, sh = -(1 << 30);
    if (kk < KTOT) {
      int ci = kk / (3 * NKv);
      int rem = kk - ci * (3 * NKv);
      int i = rem / 3;
      int k = rem - 3 * i;
      ro = (ci * Hin + s + i) * L;
      sh = (k - 1) * (1 << (s + i));
    }
    roT[kk] = ro;
    shT[kk] = sh;
  }
  __syncthreads();

  f32x4 acc[T];
#pragma unroll
  for (int t = 0; t < T; ++t) acc[t] = (f32x4){0.f, 0.f, 0.f, 0.f};

  const short* ApkS = Apk + (size_t)s * 2 * COPAD * KPAD;
  const short* arowH = ApkS + (size_t)(coBase + m0) * KPAD;
  const short* arowL = arowH + (size_t)COPAD * KPAD;
  const unsigned short* Xb = X + (size_t)b * Ci * Hin * L;

  const int lB = tid & (LT - 1);
  const int oc0 = tid / LT;
  const int nch = (KTOT + 63) >> 6;

  uint4 v0[RIT], v1[RIT], v2[RIT];
  auto gather = [&](int c0, uint4 (&pk)[RIT]) {
#pragma unroll
    for (int r = 0; r < RIT; ++r) {
      const int oct = oc0 + KO * r;
      const int kkb = (c0 << 6) + oct * 8;
      unsigned w[8];
#pragma unroll
      for (int j = 0; j < 8; ++j) {
        const int kk = kkb + j;
        const int pos = l0 + lB + shT[kk];
        const int posc = min(max(pos, 0), L - 1);
        unsigned u = (unsigned)Xb[roT[kk] + posc];
        w[j] = ((unsigned)pos < (unsigned)L) ? u : 0u;
      }
      pk[r].x = w[0] | (w[1] << 16);
      pk[r].y = w[2] | (w[3] << 16);
      pk[r].z = w[4] | (w[5] << 16);
      pk[r].w = w[6] | (w[7] << 16);
    }
  };

  gather(0, v0);
  if (nch > 1) gather(1, v1);
  for (int c0 = 0; c0 < nch; ++c0) {
#pragma unroll
    for (int r = 0; r < RIT; ++r)
      *(uint4*)(Bh + lB * 72 + (oc0 + KO * r) * 8) = v0[r];
    if (c0 + 2 < nch) gather(c0 + 2, v2);
    const int a0 = (c0 << 6) + quad * 8;
    short8v ah0 = *(const short8v*)(arowH + a0);
    short8v al0 = *(const short8v*)(arowL + a0);
    short8v ah1 = *(const short8v*)(arowH + a0 + 32);
    short8v al1 = *(const short8v*)(arowL + a0 + 32);
    __syncthreads();
#pragma unroll
    for (int t = 0; t < T; ++t) {
      const int l = m0 + 16 * t;
      short8v b0 = *(const short8v*)(Bh + l * 72 + quad * 8);
      short8v b1 = *(const short8v*)(Bh + l * 72 + 32 + quad * 8);
      acc[t] = __builtin_amdgcn_mfma_f32_16x16x32_bf16(ah0, b0, acc[t], 0, 0, 0);
      acc[t] = __builtin_amdgcn_mfma_f32_16x16x32_bf16(al0, b0, acc[t], 0, 0, 0);
      acc[t] = __builtin_amdgcn_mfma_f32_16x16x32_bf16(ah1, b1, acc[t], 0, 0, 0);
      acc[t] = __builtin_amdgcn_mfma_f32_16x16x32_bf16(al1, b1, acc[t], 0, 0, 0);
    }
    __syncthreads();
#pragma unroll
    for (int r = 0; r < RIT; ++r) {
      v0[r] = v1[r];
      v1[r] = v2[r];
    }
  }

#pragma unroll
  for (int reg = 0; reg < 4; ++reg) {
    const int co = coBase + quad * 4 + reg;
    float ss = 0.f, sq = 0.f;
    if (co < Co) {
      float* yp = Y + (((size_t)b * Co + co) * Hout + s) * L + l0;
#pragma unroll
      for (int t = 0; t < T; ++t) {
        float v = acc[t][reg];
        yp[m0 + 16 * t] = v;
        ss += v;
        sq = fmaf(v, v, sq);
      }
    }
    ss = dpp_radd<0x128>(ss);
    sq = dpp_radd<0x128>(sq);
    ss = dpp_radd<0x124>(ss);
    sq = dpp_radd<0x124>(sq);
    ss = dpp_radd<0x122>(ss);
    sq = dpp_radd<0x122>(sq);
    ss = dpp_radd<0x121>(ss);
    sq = dpp_radd<0x121>(sq);
    if (m0 == 0) {
      sCh[0][wv * 16 + quad * 4 + reg] = ss;
      sCh[1][wv * 16 + quad * 4 + reg] = sq;
    }
  }
  __syncthreads();
  if (tid < 64) {
    const int co = cog * 64 + tid;
    if (co < Co) {
      float* pp = part + (size_t)(lc & 7) * 1024;
      atomicAdd(&pp[co], sCh[0][tid]);
      atomicAdd(&pp[512 + co], sCh[1][tid]);
    }
  }
}

// ---------------------------------------------------------------------------
// gg_tail3: unrolled, atomic-free tail GConvGG (layers 9/10).
// ---------------------------------------------------------------------------
template <int NK, int L, int COSUB, int UN>
__global__ __launch_bounds__(256) void gg_tail3_kernel(
    const float* __restrict__ X, const float* __restrict__ W,
    float* __restrict__ Y, int Ci, int Co, int Hin, int NSPLIT, int ciPer,
    int partStride) {
  const int l = threadIdx.x % L;
  const int cs = threadIdx.x / L;
  const int co = blockIdx.x * COSUB + cs;
  const int s = blockIdx.y / NSPLIT;
  const int seg = blockIdx.y % NSPLIT;
  const int b = blockIdx.z;
  const int Hout = Hin - NK + 1;
  const int ciBeg = seg * ciPer;
  const int ciEnd = min(Ci, ciBeg + ciPer);

  float acc[NK];
#pragma unroll
  for (int i = 0; i < NK; ++i) acc[i] = 0.f;

  const float* wbase = W + (size_t)co * Ci * NK * 3;
  const float* xbase = X + ((size_t)b * Ci * Hin + s) * L;

  int ci = ciBeg;
  for (; ci + UN <= ciEnd; ci += UN) {
    float xv[UN][NK][3];
#pragma unroll
    for (int u = 0; u < UN; ++u) {
      const float* xr = xbase + (size_t)(ci + u) * (Hin * L);
#pragma unroll
      for (int i = 0; i < NK; ++i) {
        const int d = 1 << (s + i);
        const float* row = xr + i * L;
        xv[u][i][0] = (l >= d) ? row[l - d] : 0.f;
        xv[u][i][1] = row[l];
        xv[u][i][2] = (l + d < L) ? row[l + d] : 0.f;
      }
    }
#pragma unroll
    for (int u = 0; u < UN; ++u) {
      const float* wp = wbase + (ci + u) * (NK * 3);
#pragma unroll
      for (int i = 0; i < NK; ++i)
        acc[i] = fmaf(wp[3 * i], xv[u][i][0],
                      fmaf(wp[3 * i + 1], xv[u][i][1],
                           fmaf(wp[3 * i + 2], xv[u][i][2], acc[i])));
    }
  }
  for (; ci < ciEnd; ++ci) {
    const float* xr = xbase + (size_t)ci * (Hin * L);
    const float* wp = wbase + ci * (NK * 3);
#pragma unroll
    for (int i = 0; i < NK; ++i) {
      const int d = 1 << (s + i);
      const float* row = xr + i * L;
      float xm = (l >= d) ? row[l - d] : 0.f;
      float xc = row[l];
      float xp = (l + d < L) ? row[l + d] : 0.f;
      acc[i] = fmaf(wp[3 * i], xm,
                    fmaf(wp[3 * i + 1], xc, fmaf(wp[3 * i + 2], xp, acc[i])));
    }
  }
  float out = 0.f;
#pragma unroll
  for (int i = 0; i < NK; ++i) {
    float invd = __uint_as_float((unsigned)(127 - (s + i)) << 23);
    out = fmaf(acc[i], invd, out);
  }
  Y[(size_t)seg * partStride + (((size_t)b * Co + co) * Hout + s) * L + l] =
      out;
}

// ---------------------------------------------------------------------------
// Final: bn10+relu, mean over L, classifier
// ---------------------------------------------------------------------------
__global__ __launch_bounds__(256) void final_kernel(
    const float* __restrict__ Y, const float* __restrict__ st,
    const float* __restrict__ g, const float* __restrict__ bb,
    const float* __restrict__ w11, float* __restrict__ out) {
  const int b = blockIdx.x;
  const int tid = threadIdx.x;
  __shared__ float tch[408];
  for (int c = tid; c < 408; c += 256) {
    float m = st[c] * (1.f / 256.f);
    float v = st[512 + c] * (1.f / 256.f) - m * m;
    float sc = g[c] * rsqrtf(v + EPSBN);
    float bi = bb[c] - m * sc;
    const float* p = Y + ((size_t)b * 408 + c) * 32;
    float ssum = 0.f;
#pragma unroll
    for (int l = 0; l < 32; ++l) ssum += fmaxf(p[l] * sc + bi, 0.f);
    tch[c] = ssum * (1.f / 32.f);
  }
  __syncthreads();
  if (tid < 10) {
    float ssum = 0.f;
    for (int c = 0; c < 408; ++c) ssum += w11[tid * 408 + c] * tch[c];
    out[b * 10 + tid] = ssum;
  }
}

// ---------------------------------------------------------------------------
extern "C" void kernel_launch(void* const* d_in, const int* in_sizes, int n_in,
                              void* d_out, int out_size, void* d_ws,
                              size_t ws_size, hipStream_t stream) {
  const float* x = (const float*)d_in[0];
  const float* w1 = (const float*)d_in[1];
  const float* w2 = (const float*)d_in[2];
  const float* w3 = (const float*)d_in[3];
  const float* w4 = (const float*)d_in[4];
  const float* w5 = (const float*)d_in[5];
  const float* w6 = (const float*)d_in[6];
  const float* w7 = (const float*)d_in[7];
  const float* w8 = (const float*)d_in[8];
  const float* w9 = (const float*)d_in[9];
  const float* w10 = (const float*)d_in[10];
  const float* w11 = (const float*)d_in[11];
  const float* gg[11];
  const float* bbv[11];
  for (int i = 1; i <= 10; ++i) {
    gg[i] = (const float*)d_in[12 + 2 * (i - 1)];
    bbv[i] = (const float*)d_in[12 + 2 * (i - 1) + 1];
  }

  float* ws = (float*)d_ws;
  const size_t AR0 = 0;
  const size_t AR1 = 30081024;
  const size_t STATS = 38900000;
  float* y1 = ws + AR0;
  short* apk1 = (short*)(ws + AR1 + 460800);              // 110592 shorts
  unsigned* xpairH = (unsigned*)(ws + AR1 + 520000);      // 4110336 dw
  unsigned* xpairL = (unsigned*)(ws + AR1 + 4630336);     // 4110336 dw
  float* part1 = ws + AR1 + 8740672;                      // 512*128 fp32
  unsigned short* z1b = (unsigned short*)(ws + AR1);
  unsigned short* a3b = (unsigned short*)(ws + AR1);
  unsigned short* z3b = (unsigned short*)(ws + AR1);
  unsigned short* a5b = (unsigned short*)(ws + AR1 + 1500000);
  unsigned short* z5b = (unsigned short*)(ws + AR1);          // 522240 sh
  unsigned short* a6b = (unsigned short*)(ws + AR1 + 522240); // 626688 sh
  unsigned short* a7b = (unsigned short*)(ws + AR1 + 1148928);
  float* z8 = ws + AR1;
  float* a9 = ws + AR1 + 1775616;
  float* part9 = ws + AR1 + 1900000;   // 4 * 104448
  float* part10 = ws + AR1 + 2400000;  // 4 * 104448
  float* y2 = ws + AR0;
  float* y3 = ws + AR0 + 5849088;
  float* y4 = ws + AR0;
  float* y5 = ws + AR0 + 2088960;
  float* y6 = ws + AR0;
  float* y7 = ws + AR0 + 626688;
  float* y8 = ws + AR0 + 1253376;
  float* y9 = ws + AR0;
  float* y10 = ws + AR0 + 104448;
  short* apk2 = (short*)(ws + 12000000);
  short* apk3 = apk2 + 7 * 2 * 64 * 512;
  short* apk4 = apk3 + 7 * 2 * 64 * 192;
  short* apk5 = apk4 + 5 * 2 * 128 * 512;
  short* apk6 = apk5 + 5 * 2 * 128 * 320;   // 3*2*256*960 shorts
  short* apk7 = apk6 + 3 * 2 * 256 * 960;   // 3*2*256*640
  short* apk8 = apk7 + 3 * 2 * 256 * 640;   // 3*2*256*640
  float* st[11];
  for (int i = 1; i <= 10; ++i) st[i] = ws + STATS + (size_t)(i - 1) * 1024;
  // per-layer 8-slice stats parts for layers 2..8 (8*1024 floats each)
  float* partg = ws + STATS + 10240;
  float* part2 = partg;
  float* part3 = partg + 8192;
  float* part4 = partg + 2 * 8192;
  float* part5 = partg + 3 * 8192;
  float* part6 = partg + 4 * 8192;
  float* part7 = partg + 5 * 8192;
  float* part8 = partg + 6 * 8192;

  hipMemsetAsync((void*)(ws + STATS), 0, 10 * 1024 * sizeof(float), stream);
  hipMemsetAsync((void*)part1, 0, 512 * 128 * sizeof(float), stream);
  hipMemsetAsync((void*)partg, 0, 7 * 8192 * sizeof(float), stream);

  // ---- fused per-s pair arrays (pad_x folded), pack w1, MFMA lift
  pad_pair_kernel<<<dim3((PROW + 255) / 256, 72), 256, 0, stream>>>(
      x, xpairH, xpairL);
  pack_w1_kernel<<<(9 * 64 * 96 + 255) / 256, 256, 0, stream>>>(w1, apk1);
  lift_mfma_kernel<<<dim3(512, 9, 8), 256, 0, stream>>>(xpairH, xpairL, apk1,
                                                        y1, part1);
  reduce_stats1_kernel<<<8, 128, 0, stream>>>(part1, st[1]);
  {
    unsigned int tot = 8u * 51 * 9 * 2048;
    bnrelu_pool_bf16_kernel<<<(tot + 255) / 256, 256, 0, stream>>>(
        y1, st[1], gg[1], bbv[1], z1b, 51, 9, 8192, 1.f / 589824.f, tot);
  }
  // ---- per-s weight packs
  pack_w2_kernel<<<(7 * 64 * 512 + 255) / 256, 256, 0, stream>>>(
      w2, apk2, 51, 459, 512, 64, 7, 9);
  pack_w2_kernel<<<(7 * 64 * 192 + 255) / 256, 256, 0, stream>>>(
      w3, apk3, 51, 153, 192, 64, 7, 3);
  pack_w2_kernel<<<(5 * 128 * 512 + 255) / 256, 256, 0, stream>>>(
      w4, apk4, 102, 459, 512, 128, 5, 9);
  pack_w2_kernel<<<(5 * 128 * 320 + 255) / 256, 256, 0, stream>>>(
      w5, apk5, 102, 306, 320, 128, 5, 3);
  pack_w2_kernel<<<(3 * 256 * 960 + 255) / 256, 256, 0, stream>>>(
      w6, apk6, 204, 918, 960, 256, 3, 9);
  pack_w2_kernel<<<(3 * 256 * 640 + 255) / 256, 256, 0, stream>>>(
      w7, apk7, 204, 612, 640, 256, 3, 3);
  pack_w2_kernel<<<(3 * 256 * 640 + 255) / 256, 256, 0, stream>>>(
      w8, apk8, 204, 612, 640, 256, 3, 3);
  // ---- gg2: 51->51, H 9->7, L=2048 (fused stats)
  gg_mfma5_kernel<3, 64><<<dim3(32, 7, 8), 256, 0, stream>>>(
      z1b, apk2, y2, part2, 51, 51, 9, 2048, 32, 459, 512, 64);
  {
    unsigned int tot = 8u * 51 * 7 * 2048;
    bnrelu_bf16_parts_kernel<<<(tot + 255) / 256, 256, 0, stream>>>(
        y2, part2, gg[2], bbv[2], a3b, 51, 7 * 2048, 1.f / 114688.f, tot);
  }
  // ---- gg3: 51->51, H7, L=2048 (fused stats)
  gg_mfma5_kernel<1, 64><<<dim3(32, 7, 8), 256, 0, stream>>>(
      a3b, apk3, y3, part3, 51, 51, 7, 2048, 32, 153, 192, 64);
  {
    unsigned int tot = 8u * 51 * 7 * 512;
    bnrelu_pool_bf16_parts_kernel<<<(tot + 255) / 256, 256, 0, stream>>>(
        y3, part3, gg[3], bbv[3], z3b, 51, 7, 2048, 1.f / 114688.f, tot);
  }
  // ---- gg4: 51->102, H 7->5, L=512 (fused stats)
  gg_mfma5_kernel<3, 32><<<dim3(32, 5, 8), 256, 0, stream>>>(
      z3b, apk4, y4, part4, 51, 102, 7, 512, 16, 459, 512, 128);
  {
    unsigned int tot = 8u * 102 * 5 * 512;
    bnrelu_bf16_parts_kernel<<<(tot + 255) / 256, 256, 0, stream>>>(
        y4, part4, gg[4], bbv[4], a5b, 102, 5 * 512, 1.f / 20480.f, tot);
  }
  // ---- gg5: 102->102, H5, L=512 (fused stats)
  gg_mfma5_kernel<1, 32><<<dim3(32, 5, 8), 256, 0, stream>>>(
      a5b, apk5, y5, part5, 102, 102, 5, 512, 16, 306, 320, 128);
  {
    unsigned int tot = 8u * 102 * 5 * 128;
    bnrelu_pool_bf16_parts_kernel<<<(tot + 255) / 256, 256, 0, stream>>>(
        y5, part5, gg[5], bbv[5], z5b, 102, 5, 512, 1.f / 20480.f, tot);
  }
  // ---- gg6: 102->204, H 5->3, L=128 — MFMA + fused stats
  gg_mfma5_kernel<3, 32><<<dim3(16, 3, 8), 256, 0, stream>>>(
      z5b, apk6, y6, part6, 102, 204, 5, 128, 4, 918, 960, 256);
  {
    unsigned int tot = 8u * 204 * 3 * 128;
    bnrelu_bf16_parts_kernel<<<(tot + 255) / 256, 256, 0, stream>>>(
        y6, part6, gg[6], bbv[6], a6b, 204, 3 * 128, 1.f / 3072.f, tot);
  }
  // ---- gg7: 204->204, H3, L=128 — MFMA + fused stats
  gg_mfma5_kernel<1, 32><<<dim3(16, 3, 8), 256, 0, stream>>>(
      a6b, apk7, y7, part7, 204, 204, 3, 128, 4, 612, 640, 256);
  {
    unsigned int tot = 8u * 204 * 3 * 128;
    bnrelu_bf16_parts_kernel<<<(tot + 255) / 256, 256, 0, stream>>>(
        y7, part7, gg[7], bbv[7], a7b, 204, 3 * 128, 1.f / 3072.f, tot);
  }
  // ---- gg8: 204->204, H3, L=128 — MFMA + fused stats
  gg_mfma5_kernel<1, 32><<<dim3(16, 3, 8), 256, 0, stream>>>(
      a7b, apk8, y8, part8, 204, 204, 3, 128, 4, 612, 640, 256);
  {
    unsigned int tot = 8u * 204 * 3 * 32;
    bnrelu_pool_parts_kernel<<<(tot + 255) / 256, 256, 0, stream>>>(
        y8, part8, gg[8], bbv[8], z8, 204, 3, 128, 1.f / 3072.f, tot);
  }
  // ---- gg9: 204->408, H 3->1, L=32 (K-split x4 into partials, reduce)
  gg_tail3_kernel<3, 32, 8, 2><<<dim3(51, 4, 8), 256, 0, stream>>>(
      z8, w9, part9, 204, 408, 3, 4, 51, 104448);
  reduce_parts_kernel<<<(104448 + 255) / 256, 256, 0, stream>>>(
      part9, y9, 104448, 104448, 4);
  stats_kernel<<<dim3(408, 8, 1), 256, 0, stream>>>(y9, st[9], 408, 32, 1);
  {
    unsigned int tot = 8u * 408 * 32;
    bnrelu_kernel<<<(tot + 255) / 256, 256, 0, stream>>>(
        y9, st[9], gg[9], bbv[9], a9, 408, 32, 1.f / 256.f, tot);
  }
  // ---- gg10: 408->408, H1, L=32 (K-split x4 into partials, reduce)
  gg_tail3_kernel<1, 32, 8, 8><<<dim3(51, 4, 8), 256, 0, stream>>>(
      a9, w10, part10, 408, 408, 1, 4, 102, 104448);
  reduce_parts_kernel<<<(104448 + 255) / 256, 256, 0, stream>>>(
      part10, y10, 104448, 104448, 4);
  stats_kernel<<<dim3(408, 8, 1), 256, 0, stream>>>(y10, st[10], 408, 32, 1);
  // ---- final
  final_kernel<<<dim3(8), 256, 0, stream>>>(y10, st[10], gg[10], bbv[10], w11,
                                            (float*)d_out);
}

// Round 13
// 591.281 us; speedup vs baseline: 1.0325x; 1.0252x over previous
//
#include <hip/hip_runtime.h>
#include <hip/hip_bf16.h>

#define EPSBN 2e-5f

typedef __attribute__((ext_vector_type(8))) short short8v;
typedef __attribute__((ext_vector_type(4))) float f32x4;

__device__ inline unsigned short f2bf(float f) {
  unsigned u = __float_as_uint(f);
  unsigned r = (u + 0x7FFFu + ((u >> 16) & 1u)) >> 16;
  return (unsigned short)r;
}
__device__ inline float bf2f(unsigned short h) {
  return __uint_as_float(((unsigned)h) << 16);
}

// DPP row-rotate float add: v += rotate_within_16(v, N). VALU pipe, not LDS.
template <int CTRL>
__device__ inline float dpp_radd(float v) {
  int r = __builtin_amdgcn_update_dpp(0, __float_as_int(v), CTRL, 0xf, 0xf,
                                      true);
  return v + __int_as_float(r);
}

// ---------------------------------------------------------------------------
// Per-scale pair-packed B source (separate H/L arrays; pad_x folded in).
// ---------------------------------------------------------------------------
constexpr int XPADL = 9984;
constexpr int XPADR = 14336;
constexpr int PROW = XPADL + 32768 + XPADR;  // 57088

__global__ __launch_bounds__(256) void pad_pair_kernel(
    const float* __restrict__ x, unsigned* __restrict__ xpH,
    unsigned* __restrict__ xpL) {
  const int i = blockIdx.x * 256 + threadIdx.x;
  if (i >= PROW) return;
  const int sb = blockIdx.y;  // s*8 + b
  const int s = sb >> 3;
  const int b = sb & 7;
  const int d = 1 << s;
  const int pos0 = i - XPADL;
  const int pos1 = pos0 + d;
  float v0 = (pos0 >= 0 && pos0 < 32768) ? x[b * 32768 + pos0] : 0.f;
  float v1 = (pos1 >= 0 && pos1 < 32768) ? x[b * 32768 + pos1] : 0.f;
  unsigned u0 = __float_as_uint(v0);
  unsigned h0 = u0 >> 16;
  unsigned lo0 =
      __float_as_uint(v0 - __uint_as_float(u0 & 0xffff0000u)) >> 16;
  unsigned u1 = __float_as_uint(v1);
  unsigned h1 = u1 >> 16;
  unsigned lo1 =
      __float_as_uint(v1 - __uint_as_float(u1 & 0xffff0000u)) >> 16;
  size_t o = (size_t)sb * PROW + i;
  xpH[o] = h0 | (h1 << 16);
  xpL[o] = lo0 | (lo1 << 16);
}

// ---------------------------------------------------------------------------
// Pack w1 [51][79] -> per-s split bf16 (1/2^s folded), [s][hi/lo][64][96]
// ---------------------------------------------------------------------------
__global__ __launch_bounds__(256) void pack_w1_kernel(
    const float* __restrict__ W, short* __restrict__ A) {
  int idx = blockIdx.x * 256 + threadIdx.x;
  if (idx >= 9 * 64 * 96) return;
  int s = idx / (64 * 96);
  int rem = idx - s * 64 * 96;
  int co = rem / 96;
  int k = rem - co * 96;
  float v = 0.f;
  if (co < 51 && k < 79)
    v = W[co * 79 + k] * __uint_as_float((unsigned)(127 - s) << 23);
  unsigned short hi = f2bf(v);
  unsigned short lo = f2bf(v - bf2f(hi));
  A[(size_t)s * 2 * 64 * 96 + co * 96 + k] = (short)hi;
  A[(size_t)s * 2 * 64 * 96 + 64 * 96 + co * 96 + k] = (short)lo;
}

// ---------------------------------------------------------------------------
// lift_mfma (R10 config — measured best 124.8 µs; R12's sCh-alias barrier
// cost 2.6% for zero occupancy gain, reverted). MFMA GEMM + fused pool4 +
// DPP stats reduce. y1 fp32.
// ---------------------------------------------------------------------------
__global__ __launch_bounds__(256) void lift_mfma_kernel(
    const unsigned* __restrict__ xpH, const unsigned* __restrict__ xpL,
    const short* __restrict__ Apk1, float* __restrict__ y1,
    float* __restrict__ part1) {
  constexpr int P = 104;
  const int bid = blockIdx.x;
  const int lc = (bid & 7) * 64 + (bid >> 3);  // 512 = 8*64, bijective
  const int s = blockIdx.y;
  const int b = blockIdx.z;
  const int d = 1 << s;
  const int l0 = lc * 64;
  const int tid = threadIdx.x;
  const int lane = tid & 63;
  const int quad = lane >> 4;
  const int n0 = lane & 15;
  const int wv = tid >> 6;
  const int coBase = wv * 16;

  __shared__ __align__(16) short Bh[64 * P];
  __shared__ __align__(16) short Bl[64 * P];
  __shared__ float sCh[2][64];

  const int nB = tid & 63;
  const int rowW = ((nB & 3) << 4) | (nB >> 2);  // LDS row permutation
  const int swzW = (nB & 3) << 3;                // write slot XOR (shorts)
  const int ogu = __builtin_amdgcn_readfirstlane(tid >> 6);
  const unsigned* xqH = xpH + (size_t)(s * 8 + b) * PROW + XPADL + l0;
  const unsigned* xqL = xpL + (size_t)(s * 8 + b) * PROW + XPADL + l0;

#pragma unroll
  for (int r = 0; r < 3; ++r) {
    const int kb = (ogu + 4 * r) * 8;
    const int base = (kb - 39) * d;
    uint4 ph, pl;
    ph.x = xqH[base + nB];
    ph.y = xqH[base + 2 * d + nB];
    ph.z = xqH[base + 4 * d + nB];
    ph.w = xqH[base + 6 * d + nB];
    pl.x = xqL[base + nB];
    pl.y = xqL[base + 2 * d + nB];
    pl.z = xqL[base + 4 * d + nB];
    pl.w = xqL[base + 6 * d + nB];
    *(uint4*)(Bh + rowW * P + (kb ^ swzW)) = ph;
    *(uint4*)(Bl + rowW * P + (kb ^ swzW)) = pl;
  }

  const short* ApkS = Apk1 + (size_t)s * 2 * 64 * 96;
  const short* arowH = ApkS + (coBase + n0) * 96;
  const short* arowL = arowH + 64 * 96;

  __syncthreads();

  f32x4 acc[4];
#pragma unroll
  for (int t = 0; t < 4; ++t) acc[t] = (f32x4){0.f, 0.f, 0.f, 0.f};

#pragma unroll
  for (int ks = 0; ks < 3; ++ks) {
    short8v ah = *(const short8v*)(arowH + ks * 32 + quad * 8);
    short8v al = *(const short8v*)(arowL + ks * 32 + quad * 8);
#pragma unroll
    for (int t = 0; t < 4; ++t) {
      const int n = n0 + 16 * t;
      const int off = (ks * 32 + quad * 8) ^ (t << 3);
      short8v bh = *(const short8v*)(Bh + n * P + off);
      short8v bl = *(const short8v*)(Bl + n * P + off);
      acc[t] = __builtin_amdgcn_mfma_f32_16x16x32_bf16(ah, bh, acc[t], 0, 0, 0);
      acc[t] = __builtin_amdgcn_mfma_f32_16x16x32_bf16(ah, bl, acc[t], 0, 0, 0);
      acc[t] = __builtin_amdgcn_mfma_f32_16x16x32_bf16(al, bh, acc[t], 0, 0, 0);
    }
  }

#pragma unroll
  for (int reg = 0; reg < 4; ++reg) {
    const int co = coBase + quad * 4 + reg;
    float po = fmaxf(fmaxf(acc[0][reg], acc[1][reg]),
                     fmaxf(acc[2][reg], acc[3][reg]));
    const bool valid = (co < 51);
    if (valid) {
      y1[(((size_t)b * 51 + co) * 9 + s) * 8192 + (l0 >> 2) + n0] = po;
    }
    float us = valid ? po : 0.f;
    float sq = us * us;
    us = dpp_radd<0x128>(us);
    sq = dpp_radd<0x128>(sq);
    us = dpp_radd<0x124>(us);
    sq = dpp_radd<0x124>(sq);
    us = dpp_radd<0x122>(us);
    sq = dpp_radd<0x122>(sq);
    us = dpp_radd<0x121>(us);
    sq = dpp_radd<0x121>(sq);
    if (n0 == 0) {
      sCh[0][co] = us;
      sCh[1][co] = sq;
    }
  }
  __syncthreads();
  if (tid < 51) {
    float* pp = part1 + (size_t)lc * 128;
    atomicAdd(&pp[tid], sCh[0][tid]);
    atomicAdd(&pp[64 + tid], sCh[1][tid]);
  }
}

// ---------------------------------------------------------------------------
// Reduce the 512 lc-sliced stats partials into st.
// ---------------------------------------------------------------------------
__global__ __launch_bounds__(128) void reduce_stats1_kernel(
    const float* __restrict__ p, float* __restrict__ st) {
  const int t = threadIdx.x;
  if (t >= 102) return;
  const int k0 = blockIdx.x * 64;
  const int off = (t < 51) ? t : (64 + t - 51);
  float s = 0.f;
  for (int k = k0; k < k0 + 64; ++k) s += p[k * 128 + off];
  atomicAdd(&st[(t < 51) ? t : (512 + t - 51)], s);
}

// ---------------------------------------------------------------------------
// Per-channel sum/sumsq (layers 9/10 only)
// ---------------------------------------------------------------------------
__global__ __launch_bounds__(256) void stats_kernel(
    const float* __restrict__ Y, float* __restrict__ st, int C, int HL,
    int NS) {
  const int c = blockIdx.x, b = blockIdx.y, z = blockIdx.z;
  const int slice = HL / NS;
  const float* p = Y + ((size_t)b * C + c) * HL + (size_t)z * slice;
  float s = 0.f, q = 0.f;
  for (int i = threadIdx.x; i < slice; i += 256) {
    float v = p[i];
    s += v;
    q += v * v;
  }
#pragma unroll
  for (int off = 32; off > 0; off >>= 1) {
    s += __shfl_down(s, off, 64);
    q += __shfl_down(q, off, 64);
  }
  __shared__ float ls[4], lq[4];
  const int wid = threadIdx.x >> 6, lane = threadIdx.x & 63;
  if (lane == 0) { ls[wid] = s; lq[wid] = q; }
  __syncthreads();
  if (threadIdx.x == 0) {
    atomicAdd(&st[c], ls[0] + ls[1] + ls[2] + ls[3]);
    atomicAdd(&st[512 + c], lq[0] + lq[1] + lq[2] + lq[3]);
  }
}

// ---------------------------------------------------------------------------
// reduce NS partial buffers: y[i] = sum_k p[k*stride + i]
// ---------------------------------------------------------------------------
__global__ __launch_bounds__(256) void reduce_parts_kernel(
    const float* __restrict__ p, float* __restrict__ y, int n, int stride,
    int ns) {
  int i = blockIdx.x * 256 + threadIdx.x;
  if (i >= n) return;
  float s = 0.f;
  for (int k = 0; k < ns; ++k) s += p[(size_t)k * stride + i];
  y[i] = s;
}

// ---------------------------------------------------------------------------
// Inline 8-slice parts stats
// ---------------------------------------------------------------------------
__device__ inline void parts_bn(const float* __restrict__ pp, unsigned c,
                                float invN, const float* __restrict__ g,
                                const float* __restrict__ bb, float& sc,
                                float& bi) {
  float ssum = 0.f, sqs = 0.f;
#pragma unroll
  for (int k = 0; k < 8; ++k) {
    ssum += pp[k * 1024 + c];
    sqs += pp[k * 1024 + 512 + c];
  }
  float m = ssum * invN;
  float v = sqs * invN - m * m;
  sc = g[c] * rsqrtf(v + EPSBN);
  bi = bb[c] - m * sc;
}

// ---------------------------------------------------------------------------
// BN(train)+ReLU+pool4, fp32 out — parts stats (layer 8)
// ---------------------------------------------------------------------------
__global__ __launch_bounds__(256) void bnrelu_pool_parts_kernel(
    const float* __restrict__ Y, const float* __restrict__ pp,
    const float* __restrict__ g, const float* __restrict__ bb,
    float* __restrict__ Z, int C, int H, int Lin, float invN,
    unsigned int total) {
  unsigned int idx = blockIdx.x * 256u + threadIdx.x;
  if (idx >= total) return;
  const unsigned int Lo = (unsigned int)(Lin >> 2);
  unsigned int lo = idx % Lo;
  unsigned int r1 = idx / Lo;
  unsigned int h = r1 % (unsigned int)H;
  unsigned int r2 = r1 / (unsigned int)H;
  unsigned int c = r2 % (unsigned int)C;
  unsigned int b = r2 / (unsigned int)C;
  float sc, bi;
  parts_bn(pp, c, invN, g, bb, sc, bi);
  const float* p = Y + (((size_t)b * C + c) * H + h) * Lin + 4u * lo;
  float a0 = p[0] * sc + bi, a1 = p[1] * sc + bi;
  float a2 = p[2] * sc + bi, a3 = p[3] * sc + bi;
  float r = fmaxf(fmaxf(a0, a1), fmaxf(a2, a3));
  Z[idx] = fmaxf(r, 0.f);
}

// ---- BN+ReLU+pool4 bf16-out, parts stats (layer 3, unpadded out)
__global__ __launch_bounds__(256) void bnrelu_pool_bf16_parts_kernel(
    const float* __restrict__ Y, const float* __restrict__ pp,
    const float* __restrict__ g, const float* __restrict__ bb,
    unsigned short* __restrict__ Z, int C, int H, int Lin, float invN,
    unsigned int total) {
  unsigned int idx = blockIdx.x * 256u + threadIdx.x;
  if (idx >= total) return;
  const unsigned int Lo = (unsigned int)(Lin >> 2);
  unsigned int lo = idx % Lo;
  unsigned int r1 = idx / Lo;
  unsigned int h = r1 % (unsigned int)H;
  unsigned int r2 = r1 / (unsigned int)H;
  unsigned int c = r2 % (unsigned int)C;
  unsigned int b = r2 / (unsigned int)C;
  float sc, bi;
  parts_bn(pp, c, invN, g, bb, sc, bi);
  const float* p = Y + (((size_t)b * C + c) * H + h) * Lin + 4u * lo;
  float a0 = p[0] * sc + bi, a1 = p[1] * sc + bi;
  float a2 = p[2] * sc + bi, a3 = p[3] * sc + bi;
  float r = fmaxf(fmaxf(a0, a1), fmaxf(a2, a3));
  Z[idx] = f2bf(fmaxf(r, 0.f));
}

// ---- BN+ReLU+pool4 bf16-out PADDED rows, st stats (layer 1 -> z1b padded).
// Rows are Lp wide with PADL zero halo each side; halo zeroing folded in via
// extended thread range [total, total2).
__global__ __launch_bounds__(256) void bnrelu_pool_bf16_pad_kernel(
    const float* __restrict__ Y, const float* __restrict__ st,
    const float* __restrict__ g, const float* __restrict__ bb,
    unsigned short* __restrict__ Z, int C, int H, int Lin, float invN,
    unsigned int total, int Lp, int PADL, unsigned int total2) {
  unsigned int idx = blockIdx.x * 256u + threadIdx.x;
  if (idx >= total2) return;
  const unsigned int Lo = (unsigned int)(Lin >> 2);
  if (idx >= total) {  // halo zeroing
    unsigned int hidx = idx - total;
    unsigned int r = hidx / (unsigned int)(2 * PADL);
    unsigned int o = hidx - r * (unsigned int)(2 * PADL);
    unsigned int pos = (o < (unsigned int)PADL) ? o : (Lo + o);
    Z[(size_t)r * Lp + pos] = 0;
    return;
  }
  unsigned int lo = idx % Lo;
  unsigned int r1 = idx / Lo;
  unsigned int h = r1 % (unsigned int)H;
  unsigned int r2 = r1 / (unsigned int)H;
  unsigned int c = r2 % (unsigned int)C;
  unsigned int b = r2 / (unsigned int)C;
  float m = st[c] * invN;
  float v = st[512 + c] * invN - m * m;
  float sc = g[c] * rsqrtf(v + EPSBN);
  float bi = bb[c] - m * sc;
  const float* p = Y + (((size_t)b * C + c) * H + h) * Lin + 4u * lo;
  float a0 = p[0] * sc + bi, a1 = p[1] * sc + bi;
  float a2 = p[2] * sc + bi, a3 = p[3] * sc + bi;
  float r = fmaxf(fmaxf(a0, a1), fmaxf(a2, a3));
  Z[(((size_t)b * C + c) * H + h) * Lp + PADL + lo] = f2bf(fmaxf(r, 0.f));
}

// ---- BN+ReLU+pool4 bf16-out PADDED rows, parts stats (layer 5 -> z5b).
__global__ __launch_bounds__(256) void bnrelu_pool_bf16_parts_pad_kernel(
    const float* __restrict__ Y, const float* __restrict__ pp,
    const float* __restrict__ g, const float* __restrict__ bb,
    unsigned short* __restrict__ Z, int C, int H, int Lin, float invN,
    unsigned int total, int Lp, int PADL, unsigned int total2) {
  unsigned int idx = blockIdx.x * 256u + threadIdx.x;
  if (idx >= total2) return;
  const unsigned int Lo = (unsigned int)(Lin >> 2);
  if (idx >= total) {  // halo zeroing
    unsigned int hidx = idx - total;
    unsigned int r = hidx / (unsigned int)(2 * PADL);
    unsigned int o = hidx - r * (unsigned int)(2 * PADL);
    unsigned int pos = (o < (unsigned int)PADL) ? o : (Lo + o);
    Z[(size_t)r * Lp + pos] = 0;
    return;
  }
  unsigned int lo = idx % Lo;
  unsigned int r1 = idx / Lo;
  unsigned int h = r1 % (unsigned int)H;
  unsigned int r2 = r1 / (unsigned int)H;
  unsigned int c = r2 % (unsigned int)C;
  unsigned int b = r2 / (unsigned int)C;
  float sc, bi;
  parts_bn(pp, c, invN, g, bb, sc, bi);
  const float* p = Y + (((size_t)b * C + c) * H + h) * Lin + 4u * lo;
  float a0 = p[0] * sc + bi, a1 = p[1] * sc + bi;
  float a2 = p[2] * sc + bi, a3 = p[3] * sc + bi;
  float r = fmaxf(fmaxf(a0, a1), fmaxf(a2, a3));
  Z[(((size_t)b * C + c) * H + h) * Lp + PADL + lo] = f2bf(fmaxf(r, 0.f));
}

// ---------------------------------------------------------------------------
// BN(train)+ReLU elementwise, fp32 out (layer 9) — st stats
// ---------------------------------------------------------------------------
__global__ __launch_bounds__(256) void bnrelu_kernel(
    const float* __restrict__ Y, const float* __restrict__ st,
    const float* __restrict__ g, const float* __restrict__ bb,
    float* __restrict__ A, int C, int HL, float invN, unsigned int total) {
  unsigned int idx = blockIdx.x * 256u + threadIdx.x;
  if (idx >= total) return;
  unsigned int c = (idx / (unsigned int)HL) % (unsigned int)C;
  float m = st[c] * invN;
  float v = st[512 + c] * invN - m * m;
  float sc = g[c] * rsqrtf(v + EPSBN);
  float bi = bb[c] - m * sc;
  A[idx] = fmaxf(fmaf(Y[idx], sc, bi), 0.f);
}

// ---- BN+ReLU bf16-out, parts stats (layers 2,4,6,7)
__global__ __launch_bounds__(256) void bnrelu_bf16_parts_kernel(
    const float* __restrict__ Y, const float* __restrict__ pp,
    const float* __restrict__ g, const float* __restrict__ bb,
    unsigned short* __restrict__ A, int C, int HL, float invN,
    unsigned int total) {
  unsigned int idx = blockIdx.x * 256u + threadIdx.x;
  if (idx >= total) return;
  unsigned int c = (idx / (unsigned int)HL) % (unsigned int)C;
  float sc, bi;
  parts_bn(pp, c, invN, g, bb, sc, bi);
  A[idx] = f2bf(fmaxf(fmaf(Y[idx], sc, bi), 0.f));
}

// ---------------------------------------------------------------------------
// pack_all: all 7 per-s weight packs (w2..w8) in one launch. Segment table
// is compile-time; apk arrays are contiguous from apk2.
// ---------------------------------------------------------------------------
__global__ __launch_bounds__(256) void pack_all_kernel(
    const float* __restrict__ w2, const float* __restrict__ w3,
    const float* __restrict__ w4, const float* __restrict__ w5,
    const float* __restrict__ w6, const float* __restrict__ w7,
    const float* __restrict__ w8, short* __restrict__ apk2) {
  int idx = blockIdx.x * 256 + threadIdx.x;
  const float* W;
  short* A;
  int Co, KTOT, KPAD, COPAD, nk3;
  int r = idx;
  if (r < 229376) {
    W = w2; A = apk2; Co = 51; KTOT = 459; KPAD = 512; COPAD = 64; nk3 = 9;
  } else if ((r -= 229376) < 86016) {
    W = w3; A = apk2 + 458752; Co = 51; KTOT = 153; KPAD = 192; COPAD = 64;
    nk3 = 3;
  } else if ((r -= 86016) < 327680) {
    W = w4; A = apk2 + 630784; Co = 102; KTOT = 459; KPAD = 512; COPAD = 128;
    nk3 = 9;
  } else if ((r -= 327680) < 204800) {
    W = w5; A = apk2 + 1286144; Co = 102; KTOT = 306; KPAD = 320; COPAD = 128;
    nk3 = 3;
  } else if ((r -= 204800) < 737280) {
    W = w6; A = apk2 + 1695744; Co = 204; KTOT = 918; KPAD = 960; COPAD = 256;
    nk3 = 9;
  } else if ((r -= 737280) < 491520) {
    W = w7; A = apk2 + 3170304; Co = 204; KTOT = 612; KPAD = 640; COPAD = 256;
    nk3 = 3;
  } else if ((r -= 491520) < 491520) {
    W = w8; A = apk2 + 4153344; Co = 204; KTOT = 612; KPAD = 640; COPAD = 256;
    nk3 = 3;
  } else {
    return;
  }
  const int CK = COPAD * KPAD;
  int s = r / CK;
  int rem = r - s * CK;
  int co = rem / KPAD;
  int kk = rem - co * KPAD;
  float v = 0.f;
  if (co < Co && kk < KTOT) {
    int i = (kk % nk3) / 3;
    float scale = __uint_as_float((unsigned)(127 - (s + i)) << 23);
    v = W[co * KTOT + kk] * scale;
  }
  unsigned short hi = f2bf(v);
  unsigned short lo = f2bf(v - bf2f(hi));
  A[(size_t)s * 2 * CK + co * KPAD + kk] = (short)hi;
  A[(size_t)s * 2 * CK + CK + co * KPAD + kk] = (short)lo;
}

// ---------------------------------------------------------------------------
// gg_mfma5: bf16-input MFMA GConvGG + fused per-channel stats.
// PADDED=true: input rows are Lp wide with XP zero halo -> gather is a plain
// add+load (no clamp/select). Invalid kk (>=KTOT) read in-bounds data that
// multiplies zero-padded weights. PADDED=false: original clamp path (Lp==L).
// ---------------------------------------------------------------------------
template <int NKv, int LT, bool PADDED>
__global__ __launch_bounds__(256) void gg_mfma5_kernel(
    const unsigned short* __restrict__ X, const short* __restrict__ Apk,
    float* __restrict__ Y, float* __restrict__ part, int Ci, int Co, int Hin,
    int L, int nL, int KTOT, int KPAD, int COPAD, int Lp, int XP) {
  constexpr int T = LT / 16;
  constexpr int KO = 256 / LT;
  constexpr int RIT = 8 / KO;

  const int bx = blockIdx.x;
  const int lc = bx % nL;
  const int cog = bx / nL;
  const int s = blockIdx.y;
  const int b = blockIdx.z;
  const int Hout = Hin - NKv + 1;
  const int l0 = lc * LT;
  const int tid = threadIdx.x;
  const int lane = tid & 63;
  const int quad = lane >> 4;
  const int m0 = lane & 15;
  const int wv = tid >> 6;
  const int coBase = cog * 64 + wv * 16;

  __shared__ __align__(16) short Bh[LT * 72];
  __shared__ int roT[1024];
  __shared__ int shT[1024];
  __shared__ float sCh[2][64];

  for (int kk = tid; kk < KPAD; kk += 256) {
    int ro, sh;
    if (kk < KTOT) {
      int ci = kk / (3 * NKv);
      int rem = kk - ci * (3 * NKv);
      int i = rem / 3;
      int k = rem - 3 * i;
      ro = (ci * Hin + s + i) * Lp + XP;
      sh = (k - 1) * (1 << (s + i));
    } else {
      ro = PADDED ? XP : 0;
      sh = PADDED ? 0 : -(1 << 30);
    }
    roT[kk] = ro;
    shT[kk] = sh;
  }
  __syncthreads();

  f32x4 acc[T];
#pragma unroll
  for (int t = 0; t < T; ++t) acc[t] = (f32x4){0.f, 0.f, 0.f, 0.f};

  const short* ApkS = Apk + (size_t)s * 2 * COPAD * KPAD;
  const short* arowH = ApkS + (size_t)(coBase + m0) * KPAD;
  const short* arowL = arowH + (size_t)COPAD * KPAD;
  const unsigned short* Xb = X + (size_t)b * Ci * Hin * Lp;

  const int lB = tid & (LT - 1);
  const int oc0 = tid / LT;
  const int nch = (KTOT + 63) >> 6;

  uint4 v0[RIT], v1[RIT], v2[RIT];
  auto gather = [&](int c0, uint4 (&pk)[RIT]) {
#pragma unroll
    for (int r = 0; r < RIT; ++r) {
      const int oct = oc0 + KO * r;
      const int kkb = (c0 << 6) + oct * 8;
      unsigned w[8];
#pragma unroll
      for (int j = 0; j < 8; ++j) {
        const int kk = kkb + j;
        if (PADDED) {
          w[j] = (unsigned)Xb[roT[kk] + l0 + lB + shT[kk]];
        } else {
          const int pos = l0 + lB + shT[kk];
          const int posc = min(max(pos, 0), L - 1);
          unsigned u = (unsigned)Xb[roT[kk] + posc];
          w[j] = ((unsigned)pos < (unsigned)L) ? u : 0u;
        }
      }
      pk[r].x = w[0] | (w[1] << 16);
      pk[r].y = w[2] | (w[3] << 16);
      pk[r].z = w[4] | (w[5] << 16);
      pk[r].w = w[6] | (w[7] << 16);
    }
  };

  gather(0, v0);
  if (nch > 1) gather(1, v1);
  for (int c0 = 0; c0 < nch; ++c0) {
#pragma unroll
    for (int r = 0; r < RIT; ++r)
      *(uint4*)(Bh + lB * 72 + (oc0 + KO * r) * 8) = v0[r];
    if (c0 + 2 < nch) gather(c0 + 2, v2);
    const int a0 = (c0 << 6) + quad * 8;
    short8v ah0 = *(const short8v*)(arowH + a0);
    short8v al0 = *(const short8v*)(arowL + a0);
    short8v ah1 = *(const short8v*)(arowH + a0 + 32);
    short8v al1 = *(const short8v*)(arowL + a0 + 32);
    __syncthreads();
#pragma unroll
    for (int t = 0; t < T; ++t) {
      const int l = m0 + 16 * t;
      short8v b0 = *(const short8v*)(Bh + l * 72 + quad * 8);
      short8v b1 = *(const short8v*)(Bh + l * 72 + 32 + quad * 8);
      acc[t] = __builtin_amdgcn_mfma_f32_16x16x32_bf16(ah0, b0, acc[t], 0, 0, 0);
      acc[t] = __builtin_amdgcn_mfma_f32_16x16x32_bf16(al0, b0, acc[t], 0, 0, 0);
      acc[t] = __builtin_amdgcn_mfma_f32_16x16x32_bf16(ah1, b1, acc[t], 0, 0, 0);
      acc[t] = __builtin_amdgcn_mfma_f32_16x16x32_bf16(al1, b1, acc[t], 0, 0, 0);
    }
    __syncthreads();
#pragma unroll
    for (int r = 0; r < RIT; ++r) {
      v0[r] = v1[r];
      v1[r] = v2[r];
    }
  }

#pragma unroll
  for (int reg = 0; reg < 4; ++reg) {
    const int co = coBase + quad * 4 + reg;
    float ss = 0.f, sq = 0.f;
    if (co < Co) {
      float* yp = Y + (((size_t)b * Co + co) * Hout + s) * L + l0;
#pragma unroll
      for (int t = 0; t < T; ++t) {
        float v = acc[t][reg];
        yp[m0 + 16 * t] = v;
        ss += v;
        sq = fmaf(v, v, sq);
      }
    }
    ss = dpp_radd<0x128>(ss);
    sq = dpp_radd<0x128>(sq);
    ss = dpp_radd<0x124>(ss);
    sq = dpp_radd<0x124>(sq);
    ss = dpp_radd<0x122>(ss);
    sq = dpp_radd<0x122>(sq);
    ss = dpp_radd<0x121>(ss);
    sq = dpp_radd<0x121>(sq);
    if (m0 == 0) {
      sCh[0][wv * 16 + quad * 4 + reg] = ss;
      sCh[1][wv * 16 + quad * 4 + reg] = sq;
    }
  }
  __syncthreads();
  if (tid < 64) {
    const int co = cog * 64 + tid;
    if (co < Co) {
      float* pp = part + (size_t)(lc & 7) * 1024;
      atomicAdd(&pp[co], sCh[0][tid]);
      atomicAdd(&pp[512 + co], sCh[1][tid]);
    }
  }
}

// ---------------------------------------------------------------------------
// gg_tail3: unrolled, atomic-free tail GConvGG (layers 9/10).
// ---------------------------------------------------------------------------
template <int NK, int L, int COSUB, int UN>
__global__ __launch_bounds__(256) void gg_tail3_kernel(
    const float* __restrict__ X, const float* __restrict__ W,
    float* __restrict__ Y, int Ci, int Co, int Hin, int NSPLIT, int ciPer,
    int partStride) {
  const int l = threadIdx.x % L;
  const int cs = threadIdx.x / L;
  const int co = blockIdx.x * COSUB + cs;
  const int s = blockIdx.y / NSPLIT;
  const int seg = blockIdx.y % NSPLIT;
  const int b = blockIdx.z;
  const int Hout = Hin - NK + 1;
  const int ciBeg = seg * ciPer;
  const int ciEnd = min(Ci, ciBeg + ciPer);

  float acc[NK];
#pragma unroll
  for (int i = 0; i < NK; ++i) acc[i] = 0.f;

  const float* wbase = W + (size_t)co * Ci * NK * 3;
  const float* xbase = X + ((size_t)b * Ci * Hin + s) * L;

  int ci = ciBeg;
  for (; ci + UN <= ciEnd; ci += UN) {
    float xv[UN][NK][3];
#pragma unroll
    for (int u = 0; u < UN; ++u) {
      const float* xr = xbase + (size_t)(ci + u) * (Hin * L);
#pragma unroll
      for (int i = 0; i < NK; ++i) {
        const int d = 1 << (s + i);
        const float* row = xr + i * L;
        xv[u][i][0] = (l >= d) ? row[l - d] : 0.f;
        xv[u][i][1] = row[l];
        xv[u][i][2] = (l + d < L) ? row[l + d] : 0.f;
      }
    }
#pragma unroll
    for (int u = 0; u < UN; ++u) {
      const float* wp = wbase + (ci + u) * (NK * 3);
#pragma unroll
      for (int i = 0; i < NK; ++i)
        acc[i] = fmaf(wp[3 * i], xv[u][i][0],
                      fmaf(wp[3 * i + 1], xv[u][i][1],
                           fmaf(wp[3 * i + 2], xv[u][i][2], acc[i])));
    }
  }
  for (; ci < ciEnd; ++ci) {
    const float* xr = xbase + (size_t)ci * (Hin * L);
    const float* wp = wbase + ci * (NK * 3);
#pragma unroll
    for (int i = 0; i < NK; ++i) {
      const int d = 1 << (s + i);
      const float* row = xr + i * L;
      float xm = (l >= d) ? row[l - d] : 0.f;
      float xc = row[l];
      float xp = (l + d < L) ? row[l + d] : 0.f;
      acc[i] = fmaf(wp[3 * i], xm,
                    fmaf(wp[3 * i + 1], xc, fmaf(wp[3 * i + 2], xp, acc[i])));
    }
  }
  float out = 0.f;
#pragma unroll
  for (int i = 0; i < NK; ++i) {
    float invd = __uint_as_float((unsigned)(127 - (s + i)) << 23);
    out = fmaf(acc[i], invd, out);
  }
  Y[(size_t)seg * partStride + (((size_t)b * Co + co) * Hout + s) * L + l] =
      out;
}

// ---------------------------------------------------------------------------
// Final: bn10+relu, mean over L, classifier
// ---------------------------------------------------------------------------
__global__ __launch_bounds__(256) void final_kernel(
    const float* __restrict__ Y, const float* __restrict__ st,
    const float* __restrict__ g, const float* __restrict__ bb,
    const float* __restrict__ w11, float* __restrict__ out) {
  const int b = blockIdx.x;
  const int tid = threadIdx.x;
  __shared__ float tch[408];
  for (int c = tid; c < 408; c += 256) {
    float m = st[c] * (1.f / 256.f);
    float v = st[512 + c] * (1.f / 256.f) - m * m;
    float sc = g[c] * rsqrtf(v + EPSBN);
    float bi = bb[c] - m * sc;
    const float* p = Y + ((size_t)b * 408 + c) * 32;
    float ssum = 0.f;
#pragma unroll
    for (int l = 0; l < 32; ++l) ssum += fmaxf(p[l] * sc + bi, 0.f);
    tch[c] = ssum * (1.f / 32.f);
  }
  __syncthreads();
  if (tid < 10) {
    float ssum = 0.f;
    for (int c = 0; c < 408; ++c) ssum += w11[tid * 408 + c] * tch[c];
    out[b * 10 + tid] = ssum;
  }
}

// ---------------------------------------------------------------------------
extern "C" void kernel_launch(void* const* d_in, const int* in_sizes, int n_in,
                              void* d_out, int out_size, void* d_ws,
                              size_t ws_size, hipStream_t stream) {
  const float* x = (const float*)d_in[0];
  const float* w1 = (const float*)d_in[1];
  const float* w2 = (const float*)d_in[2];
  const float* w3 = (const float*)d_in[3];
  const float* w4 = (const float*)d_in[4];
  const float* w5 = (const float*)d_in[5];
  const float* w6 = (const float*)d_in[6];
  const float* w7 = (const float*)d_in[7];
  const float* w8 = (const float*)d_in[8];
  const float* w9 = (const float*)d_in[9];
  const float* w10 = (const float*)d_in[10];
  const float* w11 = (const float*)d_in[11];
  const float* gg[11];
  const float* bbv[11];
  for (int i = 1; i <= 10; ++i) {
    gg[i] = (const float*)d_in[12 + 2 * (i - 1)];
    bbv[i] = (const float*)d_in[12 + 2 * (i - 1) + 1];
  }

  float* ws = (float*)d_ws;
  const size_t AR0 = 0;
  const size_t AR1 = 30081024;
  const size_t STATS = 38900000;
  float* y1 = ws + AR0;
  short* apk1 = (short*)(ws + AR1 + 460800);              // 110592 shorts
  unsigned* xpairH = (unsigned*)(ws + AR1 + 520000);      // 4110336 dw
  unsigned* xpairL = (unsigned*)(ws + AR1 + 4630336);     // 4110336 dw
  float* part1 = ws + AR1 + 8740672;                      // 512*128 fp32
  unsigned short* z1b = (unsigned short*)(ws + AR1);   // padded: 9400320 sh
  unsigned short* a3b = (unsigned short*)(ws + AR1);
  unsigned short* z3b = (unsigned short*)(ws + AR1);
  unsigned short* a5b = (unsigned short*)(ws + AR1 + 1500000);
  unsigned short* z5b = (unsigned short*)(ws + AR1);   // padded: 652800 sh
  unsigned short* a6b = (unsigned short*)(ws + AR1 + 522240);
  unsigned short* a7b = (unsigned short*)(ws + AR1 + 1148928);
  float* z8 = ws + AR1;
  float* a9 = ws + AR1 + 1775616;
  float* part9 = ws + AR1 + 1900000;   // 4 * 104448
  float* part10 = ws + AR1 + 2400000;  // 4 * 104448
  float* y2 = ws + AR0;
  float* y3 = ws + AR0 + 5849088;
  float* y4 = ws + AR0;
  float* y5 = ws + AR0 + 2088960;
  float* y6 = ws + AR0;
  float* y7 = ws + AR0 + 626688;
  float* y8 = ws + AR0 + 1253376;
  float* y9 = ws + AR0;
  float* y10 = ws + AR0 + 104448;
  short* apk2 = (short*)(ws + 12000000);
  float* st[11];
  for (int i = 1; i <= 10; ++i) st[i] = ws + STATS + (size_t)(i - 1) * 1024;
  float* partg = ws + STATS + 10240;
  float* part2 = partg;
  float* part3 = partg + 8192;
  float* part4 = partg + 2 * 8192;
  float* part5 = partg + 3 * 8192;
  float* part6 = partg + 4 * 8192;
  float* part7 = partg + 5 * 8192;
  float* part8 = partg + 6 * 8192;

  hipMemsetAsync((void*)(ws + STATS), 0, 10 * 1024 * sizeof(float), stream);
  hipMemsetAsync((void*)part1, 0, 512 * 128 * sizeof(float), stream);
  hipMemsetAsync((void*)partg, 0, 7 * 8192 * sizeof(float), stream);

  // ---- fused per-s pair arrays, pack w1, MFMA lift
  pad_pair_kernel<<<dim3((PROW + 255) / 256, 72), 256, 0, stream>>>(
      x, xpairH, xpairL);
  pack_w1_kernel<<<(9 * 64 * 96 + 255) / 256, 256, 0, stream>>>(w1, apk1);
  lift_mfma_kernel<<<dim3(512, 9, 8), 256, 0, stream>>>(xpairH, xpairL, apk1,
                                                        y1, part1);
  reduce_stats1_kernel<<<8, 128, 0, stream>>>(part1, st[1]);
  // layer-1 BN+pool -> PADDED z1b (Lp=2560, PADL=256)
  {
    unsigned int tot = 8u * 51 * 9 * 2048;
    unsigned int tot2 = tot + 8u * 51 * 9 * 512;
    bnrelu_pool_bf16_pad_kernel<<<(tot2 + 255) / 256, 256, 0, stream>>>(
        y1, st[1], gg[1], bbv[1], z1b, 51, 9, 8192, 1.f / 589824.f, tot, 2560,
        256, tot2);
  }
  // ---- all per-s weight packs in one launch
  pack_all_kernel<<<(2568192 + 255) / 256, 256, 0, stream>>>(
      w2, w3, w4, w5, w6, w7, w8, apk2);
  // ---- gg2: 51->51, H 9->7, L=2048 (PADDED input, fused stats)
  gg_mfma5_kernel<3, 64, true><<<dim3(32, 7, 8), 256, 0, stream>>>(
      z1b, apk2, y2, part2, 51, 51, 9, 2048, 32, 459, 512, 64, 2560, 256);
  {
    unsigned int tot = 8u * 51 * 7 * 2048;
    bnrelu_bf16_parts_kernel<<<(tot + 255) / 256, 256, 0, stream>>>(
        y2, part2, gg[2], bbv[2], a3b, 51, 7 * 2048, 1.f / 114688.f, tot);
  }
  // ---- gg3: 51->51, H7, L=2048 (fused stats)
  gg_mfma5_kernel<1, 64, false><<<dim3(32, 7, 8), 256, 0, stream>>>(
      a3b, apk2 + 458752, y3, part3, 51, 51, 7, 2048, 32, 153, 192, 64, 2048,
      0);
  {
    unsigned int tot = 8u * 51 * 7 * 512;
    bnrelu_pool_bf16_parts_kernel<<<(tot + 255) / 256, 256, 0, stream>>>(
        y3, part3, gg[3], bbv[3], z3b, 51, 7, 2048, 1.f / 114688.f, tot);
  }
  // ---- gg4: 51->102, H 7->5, L=512 (fused stats)
  gg_mfma5_kernel<3, 32, false><<<dim3(32, 5, 8), 256, 0, stream>>>(
      z3b, apk2 + 630784, y4, part4, 51, 102, 7, 512, 16, 459, 512, 128, 512,
      0);
  {
    unsigned int tot = 8u * 102 * 5 * 512;
    bnrelu_bf16_parts_kernel<<<(tot + 255) / 256, 256, 0, stream>>>(
        y4, part4, gg[4], bbv[4], a5b, 102, 5 * 512, 1.f / 20480.f, tot);
  }
  // ---- gg5: 102->102, H5, L=512 (fused stats)
  gg_mfma5_kernel<1, 32, false><<<dim3(32, 5, 8), 256, 0, stream>>>(
      a5b, apk2 + 1286144, y5, part5, 102, 102, 5, 512, 16, 306, 320, 128,
      512, 0);
  // layer-5 BN+pool -> PADDED z5b (Lp=160, PADL=16)
  {
    unsigned int tot = 8u * 102 * 5 * 128;
    unsigned int tot2 = tot + 8u * 102 * 5 * 32;
    bnrelu_pool_bf16_parts_pad_kernel<<<(tot2 + 255) / 256, 256, 0, stream>>>(
        y5, part5, gg[5], bbv[5], z5b, 102, 5, 512, 1.f / 20480.f, tot, 160,
        16, tot2);
  }
  // ---- gg6: 102->204, H 5->3, L=128 (PADDED input, fused stats)
  gg_mfma5_kernel<3, 32, true><<<dim3(16, 3, 8), 256, 0, stream>>>(
      z5b, apk2 + 1695744, y6, part6, 102, 204, 5, 128, 4, 918, 960, 256, 160,
      16);
  {
    unsigned int tot = 8u * 204 * 3 * 128;
    bnrelu_bf16_parts_kernel<<<(tot + 255) / 256, 256, 0, stream>>>(
        y6, part6, gg[6], bbv[6], a6b, 204, 3 * 128, 1.f / 3072.f, tot);
  }
  // ---- gg7: 204->204, H3, L=128 (fused stats)
  gg_mfma5_kernel<1, 32, false><<<dim3(16, 3, 8), 256, 0, stream>>>(
      a6b, apk2 + 3170304, y7, part7, 204, 204, 3, 128, 4, 612, 640, 256, 128,
      0);
  {
    unsigned int tot = 8u * 204 * 3 * 128;
    bnrelu_bf16_parts_kernel<<<(tot + 255) / 256, 256, 0, stream>>>(
        y7, part7, gg[7], bbv[7], a7b, 204, 3 * 128, 1.f / 3072.f, tot);
  }
  // ---- gg8: 204->204, H3, L=128 (fused stats)
  gg_mfma5_kernel<1, 32, false><<<dim3(16, 3, 8), 256, 0, stream>>>(
      a7b, apk2 + 4153344, y8, part8, 204, 204, 3, 128, 4, 612, 640, 256, 128,
      0);
  {
    unsigned int tot = 8u * 204 * 3 * 32;
    bnrelu_pool_parts_kernel<<<(tot + 255) / 256, 256, 0, stream>>>(
        y8, part8, gg[8], bbv[8], z8, 204, 3, 128, 1.f / 3072.f, tot);
  }
  // ---- gg9: 204->408, H 3->1, L=32 (K-split x4 into partials, reduce)
  gg_tail3_kernel<3, 32, 8, 2><<<dim3(51, 4, 8), 256, 0, stream>>>(
      z8, w9, part9, 204, 408, 3, 4, 51, 104448);
  reduce_parts_kernel<<<(104448 + 255) / 256, 256, 0, stream>>>(
      part9, y9, 104448, 104448, 4);
  stats_kernel<<<dim3(408, 8, 1), 256, 0, stream>>>(y9, st[9], 408, 32, 1);
  {
    unsigned int tot = 8u * 408 * 32;
    bnrelu_kernel<<<(tot + 255) / 256, 256, 0, stream>>>(
        y9, st[9], gg[9], bbv[9], a9, 408, 32, 1.f / 256.f, tot);
  }
  // ---- gg10: 408->408, H1, L=32 (K-split x4 into partials, reduce)
  gg_tail3_kernel<1, 32, 8, 8><<<dim3(51, 4, 8), 256, 0, stream>>>(
      a9, w10, part10, 408, 408, 1, 4, 102, 104448);
  reduce_parts_kernel<<<(104448 + 255) / 256, 256, 0, stream>>>(
      part10, y10, 104448, 104448, 4);
  stats_kernel<<<dim3(408, 8, 1), 256, 0, stream>>>(y10, st[10], 408, 32, 1);
  // ---- final
  final_kernel<<<dim3(8), 256, 0, stream>>>(y10, st[10], gg[10], bbv[10], w11,
                                            (float*)d_out);
}